// Round 12
// baseline (762.854 us; speedup 1.0000x reference)
//
#include <hip/hip_runtime.h>
#include <math.h>

#define B_  32
#define L_  256
#define PD_ 164
#define D_  240
#define H_  16
#define NB_ 6
#define NC_ 250
#define DK_ 15
#define HID_ 480
#define LP_ 257
#define KP_ 288            // keys padded to 9*32
#define SCALE_ 0.2581988897471611f   // 1/sqrt(15)
#define LOG2E_ 1.4426950408889634f

typedef __attribute__((ext_vector_type(8))) short bf16x8;
typedef __attribute__((ext_vector_type(8))) _Float16 f16x8;
typedef __attribute__((ext_vector_type(4))) float f32x4;

static __device__ inline unsigned short f2bf(float x) {
    unsigned u = __builtin_bit_cast(unsigned, x);
    u += 0x7FFFu + ((u >> 16) & 1u);     // RNE (finite values only)
    return (unsigned short)(u >> 16);
}
static __device__ inline unsigned short f2h(float x) {
    _Float16 h = (_Float16)x;
    return __builtin_bit_cast(unsigned short, h);
}

// async global->LDS, 16B per lane; lds dest must be wave-uniform base (+lane*16)
static __device__ inline void gl2lds16(const void* g, void* l) {
    __builtin_amdgcn_global_load_lds(
        (const __attribute__((address_space(1))) unsigned int*)g,
        (__attribute__((address_space(3))) unsigned int*)l, 16, 0, 0);
}

// --------- prep_misc: cvt_x (0..8191) + pack_bias (8192..8197) + mask --------
__global__ void prep_misc(const float* __restrict__ x, unsigned short* __restrict__ xbf,
                          const float* __restrict__ bq, const float* __restrict__ bk,
                          const float* __restrict__ bv, float* __restrict__ b720,
                          float* __restrict__ mask) {
    int u = blockIdx.x;
    if (u < 8192) {
        const float* src = x + (size_t)u * PD_;
        unsigned short* dst = xbf + (size_t)u * 192;
        for (int k = threadIdx.x; k < 192; k += 64)
            dst[k] = f2bf(k < PD_ ? src[k] : 0.f);
    } else if (u < 8192 + NB_) {
        int i = u - 8192;
        for (int n = threadIdx.x; n < 720; n += 64) {
            float v = (n < 240) ? bq[i * 240 + n]
                    : (n < 480) ? bk[i * 240 + n - 240]
                                : bv[i * 240 + n - 480];
            b720[i * 720 + n] = v;
        }
    } else {
        int idx = (u - 8192 - NB_) * 64 + threadIdx.x;
        if (idx >= B_ * LP_) return;
        int b = idx / LP_, l = idx % LP_;
        if (l == 0) { mask[idx] = 0.f; return; }
        const float4* xr = (const float4*)(x + ((size_t)b * L_ + (l - 1)) * PD_);
        float4 m4 = xr[0];
        #pragma unroll 8
        for (int j = 1; j < 41; j++) {            // 41*4 = 164 exactly
            float4 v = xr[j];
            m4.x = fmaxf(m4.x, v.x); m4.y = fmaxf(m4.y, v.y);
            m4.z = fmaxf(m4.z, v.z); m4.w = fmaxf(m4.w, v.w);
        }
        float mx = fmaxf(fmaxf(m4.x, m4.y), fmaxf(m4.z, m4.w));
        mask[idx] = (mx == 0.f) ? 1.f : 0.f;
    }
}

// --------- prep_weights: 38 pretranspose jobs, LDS-tiled (coalesced) ---------
__global__ __launch_bounds__(256)
void prep_weights(const float* __restrict__ e_W1, const float* __restrict__ e_W2,
                  const float* __restrict__ Wq, const float* __restrict__ Wk,
                  const float* __restrict__ Wv, const float* __restrict__ Wo,
                  const float* __restrict__ W1, const float* __restrict__ W2,
                  unsigned short* __restrict__ We1, unsigned short* __restrict__ We2,
                  unsigned short* __restrict__ Wqkv, unsigned short* __restrict__ WoT,
                  unsigned short* __restrict__ W1T, unsigned short* __restrict__ W2T) {
    int job = blockIdx.y;
    const float* src; unsigned short* dst; int K, N, Kpad;
    if (job == 0)      { src = e_W1; dst = We1; K = PD_; N = 480; Kpad = 192; }
    else if (job == 1) { src = e_W2; dst = We2; K = 480; N = 240; Kpad = 480; }
    else {
        int i = (job - 2) % 6, w = (job - 2) / 6;
        if (w == 0)      { src = Wq + (size_t)i*240*240; dst = Wqkv + (size_t)i*768*256;           K=240; N=240; Kpad=256; }
        else if (w == 1) { src = Wk + (size_t)i*240*240; dst = Wqkv + (size_t)i*768*256 + 240*256; K=240; N=240; Kpad=256; }
        else if (w == 2) { src = Wv + (size_t)i*240*240; dst = Wqkv + (size_t)i*768*256 + 480*256; K=240; N=240; Kpad=256; }
        else if (w == 3) { src = Wo + (size_t)i*240*240; dst = WoT + (size_t)i*256*256;            K=240; N=256; Kpad=256; }
        else if (w == 4) { src = W1 + (size_t)i*240*480; dst = W1T + (size_t)i*512*256;            K=240; N=480; Kpad=256; }
        else             { src = W2 + (size_t)i*480*240; dst = W2T + (size_t)i*256*480;            K=480; N=256; Kpad=480; }
    }
    int n0 = blockIdx.x * 64;
    if (n0 >= N) return;
    int realN = (N == 256) ? 240 : N;
    __shared__ float tile[64][65];
    const int tid = threadIdx.x;
    const int lrow = tid >> 4;          // 0..15
    const int lcol = (tid & 15) * 4;    // 0..60
    const int wn   = tid >> 2;          // 0..63
    const int wq   = tid & 3;           // k-quarter
    for (int k0 = 0; k0 < Kpad; k0 += 64) {
        #pragma unroll
        for (int r4 = 0; r4 < 4; r4++) {
            int row = k0 + r4 * 16 + lrow;
            float4 v = {0.f, 0.f, 0.f, 0.f};
            if (row < K && n0 + lcol < realN)
                v = *(const float4*)(src + (size_t)row * realN + n0 + lcol);
            tile[r4 * 16 + lrow][lcol]     = v.x;
            tile[r4 * 16 + lrow][lcol + 1] = v.y;
            tile[r4 * 16 + lrow][lcol + 2] = v.z;
            tile[r4 * 16 + lrow][lcol + 3] = v.w;
        }
        __syncthreads();
        int n = n0 + wn;
        int kbase = k0 + wq * 16;
        if (n < N && kbase < Kpad) {
            unsigned short tmp[16];
            #pragma unroll
            for (int kk = 0; kk < 16; kk++)
                tmp[kk] = f2bf(tile[wq * 16 + kk][wn]);
            *(uint4*)(dst + (size_t)n * Kpad + kbase)     = *(uint4*)&tmp[0];
            *(uint4*)(dst + (size_t)n * Kpad + kbase + 8) = *(uint4*)&tmp[8];
        }
        __syncthreads();
    }
}

// ---------------- MFMA GEMM: C = A[M,Kpad]bf16 @ Bt[N,Kpad]bf16 --------------
// tile 128x64, 4 waves (2x2), K-step 32, double-buffered LDS + counted vmcnt.
// Block->tile mapping is XCD-chunk swizzled (bijective) with y-fastest order.
// flags: 1 relu, 2 accumulate fp32 C, 4 QKV-packed epilogue, 8 bf16 out
__global__ __launch_bounds__(256)
void gemm_mfma(const unsigned short* __restrict__ A,
               const unsigned short* __restrict__ Bt,
               const float* __restrict__ bias,
               float* __restrict__ C, unsigned short* __restrict__ Cbf,
               unsigned short* __restrict__ qp, unsigned short* __restrict__ kp,
               unsigned short* __restrict__ vp,
               int M, int N, int Kpad, int Cstride, int flags)
{
    __shared__ __align__(16) unsigned short As[2][128 * 32];   // 16 KB
    __shared__ __align__(16) unsigned short Bs[2][64 * 32];    // 8 KB
    const int tid = threadIdx.x;
    // ---- XCD-chunked swizzle: hw id c=flat%8 owns contiguous work chunk ----
    const int gx = gridDim.x, gy = gridDim.y;
    const int flat = blockIdx.x + gx * blockIdx.y;
    const int total = gx * gy;
    const int q8 = total >> 3, r8 = total & 7;
    const int cx = flat & 7, kx = flat >> 3;
    const int w = (cx < r8) ? (cx * (q8 + 1) + kx)
                            : (r8 * (q8 + 1) + (cx - r8) * q8 + kx);
    const int bmx = w / gy;            // x-tile (shares A across its y's)
    const int bny = w - bmx * gy;      // y-tile (y-fastest in work order)
    const int bm = bmx * 128;
    const int bn = bny * 64;
    const int zs = gridDim.z, zi = blockIdx.z;
    const int wave = tid >> 6, lane = tid & 63;
    const int wm = (wave & 1) * 64, wn = (wave >> 1) * 32;
    const int lq = lane >> 4, lr = lane & 15;

    f32x4 acc[4][2];
    #pragma unroll
    for (int i = 0; i < 4; i++)
        #pragma unroll
        for (int j = 0; j < 2; j++) acc[i][j] = (f32x4){0.f, 0.f, 0.f, 0.f};

    const int srow = lane >> 2;            // 0..15
    const int schk = (lane & 3) << 3;      // 0,8,16,24
    const int nkt = Kpad >> 5;
    const int kt0 = (nkt * zi) / zs;
    const int kt1 = (nkt * (zi + 1)) / zs;

    const unsigned short* ga0 = A + (size_t)(bm + wave * 32 + srow) * Kpad + schk + kt0 * 32;
    const unsigned short* ga1 = A + (size_t)(bm + wave * 32 + 16 + srow) * Kpad + schk + kt0 * 32;
    const unsigned short* gb  = Bt + (size_t)(bn + wave * 16 + srow) * Kpad + schk + kt0 * 32;
    char* sa = (char*)As + wave * 2048;    // per-wave slice of buffer 0
    char* sb = (char*)Bs + wave * 1024;

    #define STAGE_(bu)  do {                       \
        gl2lds16(ga0, sa + (bu) * 8192);           \
        gl2lds16(ga1, sa + (bu) * 8192 + 1024);    \
        gl2lds16(gb,  sb + (bu) * 4096);           \
        ga0 += 32; ga1 += 32; gb += 32;            \
    } while (0)

    STAGE_(0);                                  // prologue: tile kt0 -> buf 0
    int cur = 0;
    for (int kt = kt0; kt < kt1; kt++) {
        if (kt + 1 < kt1) {
            STAGE_(cur ^ 1);                    // prefetch next tile
            asm volatile("s_waitcnt vmcnt(3)" ::: "memory");   // current tile done
        } else {
            asm volatile("s_waitcnt vmcnt(0)" ::: "memory");
        }
        asm volatile("s_barrier" ::: "memory"); // all waves' stage of buf[cur] done
        const unsigned short* Asc = (const unsigned short*)((const char*)As + cur * 8192);
        const unsigned short* Bsc = (const unsigned short*)((const char*)Bs + cur * 4096);
        bf16x8 af[4], bfr[2];
        #pragma unroll
        for (int i = 0; i < 4; i++)
            af[i] = *(const bf16x8*)&Asc[(wm + i * 16 + lr) * 32 + lq * 8];
        #pragma unroll
        for (int j = 0; j < 2; j++)
            bfr[j] = *(const bf16x8*)&Bsc[(wn + j * 16 + lr) * 32 + lq * 8];
        #pragma unroll
        for (int i = 0; i < 4; i++)
            #pragma unroll
            for (int j = 0; j < 2; j++)
                acc[i][j] = __builtin_amdgcn_mfma_f32_16x16x32_bf16(af[i], bfr[j], acc[i][j], 0, 0, 0);
        asm volatile("s_barrier" ::: "memory"); // all waves done reading buf[cur]
        cur ^= 1;
    }
    #undef STAGE_

    if (flags & 4) {                       // QKV packed epilogue (N=720)
        #pragma unroll
        for (int j = 0; j < 2; j++) {
            int n = bn + wn + j * 16 + lr;
            if (n >= N) continue;
            int which = n / 240;
            int rem = n - which * 240;
            int hh = rem / 15;
            int c = rem - hh * 15;
            unsigned short* dst = (which == 0) ? qp : (which == 1) ? kp : vp;
            float bias_n = bias[n];
            float mult = (which == 0) ? (SCALE_ * LOG2E_) : 1.f;
            #pragma unroll
            for (int i = 0; i < 4; i++)
                #pragma unroll
                for (int r = 0; r < 4; r++) {
                    int m = bm + wm + i * 16 + lq * 4 + r;
                    if (m >= M) continue;
                    float s = (acc[i][j][r] + bias_n) * mult;
                    int b = m / LP_, l = m - b * LP_;
                    unsigned short bits = (which == 2) ? f2h(s) : f2bf(s);
                    dst[(((size_t)b * H_ + hh) * LP_ + l) * 16 + c] = bits;
                }
        }
    } else if (flags & 8) {                // bf16 output
        #pragma unroll
        for (int i = 0; i < 4; i++)
            #pragma unroll
            for (int j = 0; j < 2; j++) {
                int n = bn + wn + j * 16 + lr;
                if (n >= N) continue;
                float bias_n = bias ? bias[n] : 0.f;
                #pragma unroll
                for (int r = 0; r < 4; r++) {
                    int m = bm + wm + i * 16 + lq * 4 + r;
                    if (m >= M) continue;
                    float s = acc[i][j][r] + bias_n;
                    if (flags & 1) s = fmaxf(s, 0.f);
                    Cbf[(size_t)m * Cstride + n] = f2bf(s);
                }
            }
    } else {                               // fp32 output (optionally accumulate)
        #pragma unroll
        for (int i = 0; i < 4; i++)
            #pragma unroll
            for (int j = 0; j < 2; j++) {
                int n = bn + wn + j * 16 + lr;
                if (n >= N) continue;
                float bias_n = (bias && zi == 0) ? bias[n] : 0.f;
                #pragma unroll
                for (int r = 0; r < 4; r++) {
                    int m = bm + wm + i * 16 + lq * 4 + r;
                    if (m >= M) continue;
                    float s = acc[i][j][r] + bias_n;
                    if (flags & 1) s = fmaxf(s, 0.f);
                    size_t off = (size_t)m * Cstride + n;
                    if (flags & 2) {
                        if (zs > 1) atomicAdd(&C[off], s);
                        else C[off] += s;
                    } else C[off] = s;
                }
            }
    }
}

// -------- gemm_row_ln: full-row tile 64x240 (N padded 256), one block per
// 64 rows, 4 waves x 16 rows x full width, acc[16]. Epilogue:
// v = acc + bias + h (residual), h = v, in-register row-LN (shfl over the
// 16 lr-lanes that share a row: col=lr, row=lq*4+r), ybf = LN(v) bf16.
// flags: 1 = write ybf (LN output); else h-update only.
__global__ __launch_bounds__(256)
void gemm_row_ln(const unsigned short* __restrict__ A,
                 const unsigned short* __restrict__ Bt,
                 const float* __restrict__ bias,
                 float* __restrict__ h, unsigned short* __restrict__ ybf,
                 const float* __restrict__ lng, const float* __restrict__ lnb,
                 int M, int Kpad, int flags)
{
    __shared__ __align__(16) unsigned short As[2][64 * 32];    // 8 KB
    __shared__ __align__(16) unsigned short Bs[2][256 * 32];   // 32 KB
    const int tid = threadIdx.x;
    const int bm = blockIdx.x * 64;
    const int wave = tid >> 6, lane = tid & 63;
    const int wm = wave * 16;
    const int lq = lane >> 4, lr = lane & 15;
    const int srow = lane >> 2, schk = (lane & 3) << 3;
    const int nkt = Kpad >> 5;

    f32x4 acc[16];
    #pragma unroll
    for (int j = 0; j < 16; j++) acc[j] = (f32x4){0.f, 0.f, 0.f, 0.f};

    const unsigned short* ga0 = A + (size_t)(bm + wm + srow) * Kpad + schk;
    const unsigned short* gb0 = Bt + (size_t)(wave * 64 + srow) * Kpad + schk;
    char* sa = (char*)As + wave * 1024;
    char* sb = (char*)Bs + wave * 4096;

    #define STAGE_(bu)  do {                                      \
        gl2lds16(ga0, sa + (bu) * 4096);                          \
        gl2lds16(gb0,                   sb + (bu) * 16384);       \
        gl2lds16(gb0 + (size_t)16*Kpad, sb + (bu) * 16384 + 1024);\
        gl2lds16(gb0 + (size_t)32*Kpad, sb + (bu) * 16384 + 2048);\
        gl2lds16(gb0 + (size_t)48*Kpad, sb + (bu) * 16384 + 3072);\
        ga0 += 32; gb0 += 32;                                     \
    } while (0)

    STAGE_(0);
    int cur = 0;
    for (int kt = 0; kt < nkt; kt++) {
        if (kt + 1 < nkt) {
            STAGE_(cur ^ 1);
            asm volatile("s_waitcnt vmcnt(5)" ::: "memory");
        } else {
            asm volatile("s_waitcnt vmcnt(0)" ::: "memory");
        }
        asm volatile("s_barrier" ::: "memory");
        const unsigned short* Asc = (const unsigned short*)((const char*)As + cur * 4096);
        const unsigned short* Bsc = (const unsigned short*)((const char*)Bs + cur * 16384);
        bf16x8 af = *(const bf16x8*)&Asc[(wm + lr) * 32 + lq * 8];
        #pragma unroll
        for (int j = 0; j < 16; j++) {
            bf16x8 bf = *(const bf16x8*)&Bsc[(j * 16 + lr) * 32 + lq * 8];
            acc[j] = __builtin_amdgcn_mfma_f32_16x16x32_bf16(af, bf, acc[j], 0, 0, 0);
        }
        asm volatile("s_barrier" ::: "memory");
        cur ^= 1;
    }
    #undef STAGE_

    // ---- epilogue: residual + h write + in-register row-LN -> ybf ----
    float biasj[15], gj[15], bj[15];
    #pragma unroll
    for (int j = 0; j < 15; j++) {
        int n = j * 16 + lr;
        biasj[j] = bias[n];
        if (flags & 1) { gj[j] = lng[n]; bj[j] = lnb[n]; }
    }
    #pragma unroll
    for (int r = 0; r < 4; r++) {
        const int row = bm + wm + lq * 4 + r;
        if (row >= M) continue;          // uniform across the 16 lr-lanes
        float v[15];
        float s = 0.f;
        #pragma unroll
        for (int j = 0; j < 15; j++) {
            v[j] = acc[j][r] + biasj[j] + h[(size_t)row * 240 + j * 16 + lr];
            s += v[j];
        }
        s += __shfl_xor(s, 1); s += __shfl_xor(s, 2);
        s += __shfl_xor(s, 4); s += __shfl_xor(s, 8);
        #pragma unroll
        for (int j = 0; j < 15; j++)
            h[(size_t)row * 240 + j * 16 + lr] = v[j];
        if (flags & 1) {
            const float mean = s * (1.f / 240.f);
            float q = 0.f;
            #pragma unroll
            for (int j = 0; j < 15; j++) { float d = v[j] - mean; q += d * d; }
            q += __shfl_xor(q, 1); q += __shfl_xor(q, 2);
            q += __shfl_xor(q, 4); q += __shfl_xor(q, 8);
            const float rs = rsqrtf(q * (1.f / 240.f) + 1e-5f);
            #pragma unroll
            for (int j = 0; j < 15; j++)
                ybf[(size_t)row * 256 + j * 16 + lr] =
                    f2bf((v[j] - mean) * rs * gj[j] + bj[j]);
            ybf[(size_t)row * 256 + 240 + lr] = 0;   // pad cols
        }
    }
}

// -------- ffn_fused: per block 32 rows (257 blocks = 8224 exactly).
// Phase 1: t = relu(ybf[32x256] @ W1T^T + b1) -> LDS bf16 [32][488].
//   4 waves = 2 row-groups x 2 col-halves; acc1[15]/wave; K-step 32, 8 steps,
//   DOUBLE-buffered staging + counted vmcnt (waves 0,1 also stage A: 9 loads;
//   waves 2,3: 8 loads).
// Phase 2: out = t @ W2T^T (K=480, 15 steps); waves 0,1 compute (acc2[15]);
//   all 4 waves stage B2 double-buffered (4 loads each, vmcnt(4)).
//   Epilogue = residual + h + row-LN -> ybf (flags&1), same as gemm_row_ln.
__global__ __launch_bounds__(256)
void ffn_fused(const unsigned short* __restrict__ ybf_in,
               const unsigned short* __restrict__ W1t,
               const float* __restrict__ b1,
               const unsigned short* __restrict__ W2t,
               const float* __restrict__ b2,
               float* __restrict__ h, unsigned short* __restrict__ ybf,
               const float* __restrict__ lng, const float* __restrict__ lnb,
               int flags)
{
    __shared__ __align__(16) unsigned short Tl[32 * 488];      // 31.2 KB
    __shared__ __align__(16) unsigned short Ad[2][32 * 32];    // 4 KB
    __shared__ __align__(16) unsigned short B1d[2][512 * 32];  // 64 KB (phase2: B2 dbuf)
    const int tid = threadIdx.x;
    const int bm = blockIdx.x * 32;
    const int wave = tid >> 6, lane = tid & 63;
    const int rg = wave >> 1, ch = wave & 1;   // row-group, col-half
    const int lq = lane >> 4, lr = lane & 15;
    const int srow = lane >> 2, schk = (lane & 3) << 3;

    // ---------------- phase 1: t = relu(ybf @ W1T + b1) ----------------
    f32x4 acc1[15];
    #pragma unroll
    for (int j = 0; j < 15; j++) acc1[j] = (f32x4){0.f, 0.f, 0.f, 0.f};

    const unsigned short* gaA = ybf_in + (size_t)(bm + wave * 16 + srow) * 256 + schk;
    const unsigned short* gb1 = W1t + (size_t)(wave * 128 + srow) * 256 + schk;

    #define STAGE1_(bu)  do {                                                  \
        if (wave < 2) gl2lds16(gaA, (char*)&Ad[bu][0] + wave * 1024);          \
        _Pragma("unroll")                                                      \
        for (int s = 0; s < 8; s++)                                            \
            gl2lds16(gb1 + (size_t)s * 16 * 256,                               \
                     (char*)&B1d[bu][0] + (wave * 8 + s) * 1024);              \
        gaA += 32; gb1 += 32;                                                  \
    } while (0)

    STAGE1_(0);
    int cur = 0;
    for (int kt = 0; kt < 8; kt++) {
        if (kt + 1 < 8) {
            STAGE1_(cur ^ 1);
            if (wave < 2) { asm volatile("s_waitcnt vmcnt(9)" ::: "memory"); }
            else          { asm volatile("s_waitcnt vmcnt(8)" ::: "memory"); }
        } else {
            asm volatile("s_waitcnt vmcnt(0)" ::: "memory");
        }
        asm volatile("s_barrier" ::: "memory");
        bf16x8 af = *(const bf16x8*)&Ad[cur][(rg * 16 + lr) * 32 + lq * 8];
        #pragma unroll
        for (int j = 0; j < 15; j++) {
            bf16x8 bf = *(const bf16x8*)&B1d[cur][(ch * 240 + j * 16 + lr) * 32 + lq * 8];
            acc1[j] = __builtin_amdgcn_mfma_f32_16x16x32_bf16(af, bf, acc1[j], 0, 0, 0);
        }
        asm volatile("s_barrier" ::: "memory");
        cur ^= 1;
    }
    #undef STAGE1_

    // write t = relu(acc1 + b1) to LDS bf16 [32][488]
    #pragma unroll
    for (int j = 0; j < 15; j++) {
        const int col = ch * 240 + j * 16 + lr;
        const float bb = b1[col];
        #pragma unroll
        for (int r = 0; r < 4; r++) {
            const int row = rg * 16 + lq * 4 + r;
            Tl[row * 488 + col] = f2bf(fmaxf(acc1[j][r] + bb, 0.f));
        }
    }
    __syncthreads();   // t complete; B1d region now reusable as B2 dbuf

    // ---------------- phase 2: out = t @ W2T + b2, residual + LN --------
    f32x4 acc2[15];
    #pragma unroll
    for (int j = 0; j < 15; j++) acc2[j] = (f32x4){0.f, 0.f, 0.f, 0.f};

    const unsigned short* gb2 = W2t + (size_t)(wave * 64 + srow) * 480 + schk;
    char* B2base = (char*)&B1d[0][0];          // [2][256*32] dbuf inside B1d

    #define STAGE2_(bu)  do {                                                  \
        _Pragma("unroll")                                                      \
        for (int s = 0; s < 4; s++)                                            \
            gl2lds16(gb2 + (size_t)s * 16 * 480,                               \
                     B2base + (bu) * 16384 + (wave * 4 + s) * 1024);           \
        gb2 += 32;                                                             \
    } while (0)

    STAGE2_(0);
    cur = 0;
    for (int kt = 0; kt < 15; kt++) {
        if (kt + 1 < 15) {
            STAGE2_(cur ^ 1);
            asm volatile("s_waitcnt vmcnt(4)" ::: "memory");
        } else {
            asm volatile("s_waitcnt vmcnt(0)" ::: "memory");
        }
        asm volatile("s_barrier" ::: "memory");
        if (wave < 2) {
            const unsigned short* B2c = (const unsigned short*)(B2base + cur * 16384);
            bf16x8 af = *(const bf16x8*)&Tl[(wave * 16 + lr) * 488 + kt * 32 + lq * 8];
            #pragma unroll
            for (int j = 0; j < 15; j++) {
                bf16x8 bf = *(const bf16x8*)&B2c[(j * 16 + lr) * 32 + lq * 8];
                acc2[j] = __builtin_amdgcn_mfma_f32_16x16x32_bf16(af, bf, acc2[j], 0, 0, 0);
            }
        }
        asm volatile("s_barrier" ::: "memory");
        cur ^= 1;
    }
    #undef STAGE2_

    if (wave >= 2) return;
    // epilogue: rows bm + wave*16 + lq*4 + r  (identical math to gemm_row_ln)
    float biasj[15], gj[15], bj[15];
    #pragma unroll
    for (int j = 0; j < 15; j++) {
        int n = j * 16 + lr;
        biasj[j] = b2[n];
        if (flags & 1) { gj[j] = lng[n]; bj[j] = lnb[n]; }
    }
    #pragma unroll
    for (int r = 0; r < 4; r++) {
        const int row = bm + wave * 16 + lq * 4 + r;
        float v[15];
        float s = 0.f;
        #pragma unroll
        for (int j = 0; j < 15; j++) {
            v[j] = acc2[j][r] + biasj[j] + h[(size_t)row * 240 + j * 16 + lr];
            s += v[j];
        }
        s += __shfl_xor(s, 1); s += __shfl_xor(s, 2);
        s += __shfl_xor(s, 4); s += __shfl_xor(s, 8);
        #pragma unroll
        for (int j = 0; j < 15; j++)
            h[(size_t)row * 240 + j * 16 + lr] = v[j];
        if (flags & 1) {
            const float mean = s * (1.f / 240.f);
            float q = 0.f;
            #pragma unroll
            for (int j = 0; j < 15; j++) { float d = v[j] - mean; q += d * d; }
            q += __shfl_xor(q, 1); q += __shfl_xor(q, 2);
            q += __shfl_xor(q, 4); q += __shfl_xor(q, 8);
            const float rs = rsqrtf(q * (1.f / 240.f) + 1e-5f);
            #pragma unroll
            for (int j = 0; j < 15; j++)
                ybf[(size_t)row * 256 + j * 16 + lr] =
                    f2bf((v[j] - mean) * rs * gj[j] + bj[j]);
            ybf[(size_t)row * 256 + 240 + lr] = 0;   // pad cols
        }
    }
}

// ------------- LN480+relu: wave-per-row, fp32 in -> bf16 out [rows][480] -----
__global__ __launch_bounds__(256)
void ln480(const float* __restrict__ in, unsigned short* __restrict__ out,
           const float* __restrict__ g, const float* __restrict__ bb) {
    const int row = blockIdx.x * 4 + (threadIdx.x >> 6);
    const int lane = threadIdx.x & 63;
    const float* x = in + (size_t)row * 480;
    float4 va = {0.f,0.f,0.f,0.f}, vb = {0.f,0.f,0.f,0.f};
    if (lane < 60) {
        va = *(const float4*)(x + lane * 8);
        vb = *(const float4*)(x + lane * 8 + 4);
    }
    float s = ((va.x + va.y) + (va.z + va.w)) + ((vb.x + vb.y) + (vb.z + vb.w));
    #pragma unroll
    for (int off = 32; off; off >>= 1) s += __shfl_xor(s, off);
    const float mean = s * (1.f / 480.f);
    float4 da, db;
    da.x = va.x - mean; da.y = va.y - mean; da.z = va.z - mean; da.w = va.w - mean;
    db.x = vb.x - mean; db.y = vb.y - mean; db.z = vb.z - mean; db.w = vb.w - mean;
    float vs = (lane < 60) ? ((da.x*da.x + da.y*da.y) + (da.z*da.z + da.w*da.w)) +
                             ((db.x*db.x + db.y*db.y) + (db.z*db.z + db.w*db.w)) : 0.f;
    #pragma unroll
    for (int off = 32; off; off >>= 1) vs += __shfl_xor(vs, off);
    const float rs = rsqrtf(vs * (1.f / 480.f) + 1e-5f);
    if (lane < 60) {
        float4 ga = *(const float4*)(g + lane * 8);
        float4 gb = *(const float4*)(g + lane * 8 + 4);
        float4 ba = *(const float4*)(bb + lane * 8);
        float4 b2 = *(const float4*)(bb + lane * 8 + 4);
        ushort4 oa, ob;
        oa.x = f2bf(fmaxf(da.x * rs * ga.x + ba.x, 0.f));
        oa.y = f2bf(fmaxf(da.y * rs * ga.y + ba.y, 0.f));
        oa.z = f2bf(fmaxf(da.z * rs * ga.z + ba.z, 0.f));
        oa.w = f2bf(fmaxf(da.w * rs * ga.w + ba.w, 0.f));
        ob.x = f2bf(fmaxf(db.x * rs * gb.x + b2.x, 0.f));
        ob.y = f2bf(fmaxf(db.y * rs * gb.y + b2.y, 0.f));
        ob.z = f2bf(fmaxf(db.z * rs * gb.z + b2.z, 0.f));
        ob.w = f2bf(fmaxf(db.w * rs * gb.w + b2.w, 0.f));
        *(ushort4*)(out + (size_t)row * 480 + lane * 8) = oa;
        *(ushort4*)(out + (size_t)row * 480 + lane * 8 + 4) = ob;
    }
}

// -------- embed finish: wave-per-row LN(g2)+relu+pos (cls for l==0),
// then layer-0 ln1 of the same row in-register -> ybf. lanes 60..62 also
// write q/k/v col-15 constants (replaces attn_init).
__global__ __launch_bounds__(256)
void embed_finish(const float* __restrict__ tmp, const float* __restrict__ mask,
                  const float* __restrict__ g, const float* __restrict__ bb,
                  const float* __restrict__ pos, const float* __restrict__ cls,
                  const float* __restrict__ l1g, const float* __restrict__ l1b,
                  float* __restrict__ h, unsigned short* __restrict__ ybf,
                  unsigned short* __restrict__ qp, unsigned short* __restrict__ kp,
                  unsigned short* __restrict__ vp) {
    const int row = blockIdx.x * 4 + (threadIdx.x >> 6);
    const int lane = threadIdx.x & 63;
    const int b = row / LP_, l = row - b * LP_;
    float* outr = h + (size_t)row * 240;

    if (lane >= 60 && lane <= 62) {
        unsigned short bits;
        unsigned short* dst;
        if (lane == 60) { bits = f2bf(LOG2E_); dst = qp; }
        else if (lane == 61) { bits = (mask[row] != 0.f) ? f2bf(-10000.f) : 0; dst = kp; }
        else { bits = f2h(1.f); dst = vp; }
        #pragma unroll
        for (int hh = 0; hh < H_; hh++)
            dst[(((size_t)b * H_ + hh) * LP_ + l) * 16 + 15] = bits;
    }

    float4 o = {0.f, 0.f, 0.f, 0.f};
    if (l == 0) {
        if (lane < 60) o = *(const float4*)(cls + lane * 4);
    } else {
        const float* x = tmp + ((size_t)b * L_ + (l - 1)) * 240;
        float4 v = {0.f, 0.f, 0.f, 0.f};
        if (lane < 60) v = *(const float4*)(x + lane * 4);
        float s = (v.x + v.y) + (v.z + v.w);
        #pragma unroll
        for (int off = 32; off; off >>= 1) s += __shfl_xor(s, off);
        const float mean = s * (1.f / 240.f);
        float4 d;
        d.x = v.x - mean; d.y = v.y - mean; d.z = v.z - mean; d.w = v.w - mean;
        float vs = (lane < 60) ? (d.x * d.x + d.y * d.y) + (d.z * d.z + d.w * d.w) : 0.f;
        #pragma unroll
        for (int off = 32; off; off >>= 1) vs += __shfl_xor(vs, off);
        const float rs = rsqrtf(vs * (1.f / 240.f) + 1e-5f);
        if (lane < 60) {
            float4 g4 = *(const float4*)(g + lane * 4);
            float4 b4 = *(const float4*)(bb + lane * 4);
            float4 p4 = *(const float4*)(pos + (size_t)(l - 1) * 240 + lane * 4);
            o.x = fmaxf(d.x * rs * g4.x + b4.x, 0.f) + p4.x;
            o.y = fmaxf(d.y * rs * g4.y + b4.y, 0.f) + p4.y;
            o.z = fmaxf(d.z * rs * g4.z + b4.z, 0.f) + p4.z;
            o.w = fmaxf(d.w * rs * g4.w + b4.w, 0.f) + p4.w;
        }
    }
    if (lane < 60) *(float4*)(outr + lane * 4) = o;

    // ---- layer-0 ln1 of this row (value already in registers) ----
    float s1 = (o.x + o.y) + (o.z + o.w);
    #pragma unroll
    for (int off = 32; off; off >>= 1) s1 += __shfl_xor(s1, off);
    const float mean1 = s1 * (1.f / 240.f);
    float4 d1;
    d1.x = o.x - mean1; d1.y = o.y - mean1; d1.z = o.z - mean1; d1.w = o.w - mean1;
    float vs1 = (lane < 60) ? (d1.x * d1.x + d1.y * d1.y) + (d1.z * d1.z + d1.w * d1.w) : 0.f;
    #pragma unroll
    for (int off = 32; off; off >>= 1) vs1 += __shfl_xor(vs1, off);
    const float rs1 = rsqrtf(vs1 * (1.f / 240.f) + 1e-5f);
    ushort4 o4 = {0, 0, 0, 0};
    if (lane < 60) {
        float4 g4 = *(const float4*)(l1g + lane * 4);
        float4 b4 = *(const float4*)(l1b + lane * 4);
        o4.x = f2bf(d1.x * rs1 * g4.x + b4.x);
        o4.y = f2bf(d1.y * rs1 * g4.y + b4.y);
        o4.z = f2bf(d1.z * rs1 * g4.z + b4.z);
        o4.w = f2bf(d1.w * rs1 * g4.w + b4.w);
    }
    *(ushort4*)(ybf + (size_t)row * 256 + lane * 4) = o4;
}

// ---------------- MFMA flash attention: block per (b,h), 4 waves -------------
__global__ __launch_bounds__(256)
void attn_mfma(const unsigned short* __restrict__ qp, const unsigned short* __restrict__ kp,
               const unsigned short* __restrict__ vp, unsigned short* __restrict__ obf)
{
    __shared__ __align__(16) unsigned short Kl[KP_ * 24];    // 13.5 KB
    __shared__ __align__(16) unsigned short Vt[16 * 296];    // 9.25 KB  V^T f16
    __shared__ __align__(16) unsigned short Pl[4][16 * 296]; // 37 KB    P f16 per wave
    const int hh = blockIdx.x, b = blockIdx.y;
    const int tid = threadIdx.x;
    const int wave = tid >> 6, lane = tid & 63;
    const int lq = lane >> 4, lr = lane & 15;
    const size_t base = ((size_t)b * H_ + hh) * LP_ * 16;

    for (int key = tid; key < KP_; key += 256) {
        uint4 z = {0u, 0u, 0u, 0u};
        uint4 k0 = z, k1 = z, v0 = z, v1 = z;
        if (key < LP_) {
            k0 = *(const uint4*)(kp + base + (size_t)key * 16);
            k1 = *(const uint4*)(kp + base + (size_t)key * 16 + 8);
            v0 = *(const uint4*)(vp + base + (size_t)key * 16);
            v1 = *(const uint4*)(vp + base + (size_t)key * 16 + 8);
        } else {
            k1.w = 0xC61C0000u;            // elem15 = bf16(-10000) sentinel
        }
        *(uint4*)&Kl[key * 24] = k0;
        *(uint4*)&Kl[key * 24 + 8] = k1;
        unsigned short vs[8];
        *(uint4*)vs = v0;
        #pragma unroll
        for (int d = 0; d < 8; d++) Vt[d * 296 + key] = vs[d];
        *(uint4*)vs = v1;
        #pragma unroll
        for (int d = 0; d < 8; d++) Vt[(d + 8) * 296 + key] = vs[d];
    }
    __syncthreads();

    unsigned short* Pw = &Pl[wave][0];
    {   // keys 272..287 are pure padding every qt: zero their P once per wave
        int r = lane >> 2, c0 = 272 + (lane & 3) * 4;
        ushort4 z4 = {0, 0, 0, 0};
        *(ushort4*)&Pw[r * 296 + c0] = z4;
    }
    for (int qt = wave; qt < 17; qt += 4) {
        const int qrow = qt * 16 + lr;
        bf16x8 aq = {0, 0, 0, 0, 0, 0, 0, 0};
        if (lq < 2)
            aq = *(const bf16x8*)(qp + base + (size_t)qrow * 16 + lq * 8);
        for (int kt = 0; kt < 17; kt++) {      // kt=17 tile is all padding: skipped
            bf16x8 bk = {0, 0, 0, 0, 0, 0, 0, 0};
            if (lq < 2)
                bk = *(const bf16x8*)&Kl[(kt * 16 + lr) * 24 + lq * 8];
            f32x4 sacc = {0.f, 0.f, 0.f, 0.f};
            sacc = __builtin_amdgcn_mfma_f32_16x16x32_bf16(aq, bk, sacc, 0, 0, 0);
            #pragma unroll
            for (int r = 0; r < 4; r++)
                Pw[(lq * 4 + r) * 296 + kt * 16 + lr] = f2h(exp2f(sacc[r]));
        }
        asm volatile("s_waitcnt lgkmcnt(0)" ::: "memory");
        f32x4 o = {0.f, 0.f, 0.f, 0.f};
        __builtin_amdgcn_s_setprio(1);
        #pragma unroll
        for (int ks = 0; ks < 9; ks++) {
            f16x8 ap = *(const f16x8*)&Pw[lr * 296 + ks * 32 + lq * 8];
            f16x8 bv = *(const f16x8*)&Vt[lr * 296 + ks * 32 + lq * 8];
            o = __builtin_amdgcn_mfma_f32_16x16x32_f16(ap, bv, o, 0, 0, 0);
        }
        __builtin_amdgcn_s_setprio(0);
        asm volatile("s_waitcnt lgkmcnt(0)" ::: "memory");
        #pragma unroll
        for (int r = 0; r < 4; r++) {
            float denom = __shfl(o[r], lane | 15);
            int q = qt * 16 + lq * 4 + r;
            if (q < LP_ && lr < 15)
                obf[((size_t)b * LP_ + q) * 256 + hh * DK_ + lr] = f2bf(o[r] / denom);
        }
    }
    // zero pad cols 240..255 (once per row, by hh==0 block)
    if (hh == 0) {
        for (int q = tid; q < LP_; q += 256) {
            uint4 z = {0u, 0u, 0u, 0u};
            *(uint4*)(obf + ((size_t)b * LP_ + q) * 256 + 240) = z;
            *(uint4*)(obf + ((size_t)b * LP_ + q) * 256 + 248) = z;
        }
    }
}

// ---------------- masked mean pool (partial) ---------------------------------
__global__ void pool_partial(const float* __restrict__ h, const float* __restrict__ mask,
                             float* __restrict__ partial) {
    int b = blockIdx.x, slice = blockIdx.y;
    int d = threadIdx.x;
    if (d >= D_) return;
    float s = 0.f;
    int l0 = slice * 29;
    for (int i = 0; i < 29; i++) {
        int l = l0 + i;
        if (l < LP_ && mask[b * LP_ + l] == 0.f)
            s += h[((size_t)b * LP_ + l) * D_ + d];
    }
    partial[((size_t)b * 9 + slice) * D_ + d] = s;
}

// ---------------- pool finalize + logits -------------------------------------
__global__ __launch_bounds__(256)
void pool_logits(const float* __restrict__ partial, const float* __restrict__ mask,
                 const float* __restrict__ W, const float* __restrict__ bias,
                 float* __restrict__ out) {
    int b = blockIdx.x;
    int t = threadIdx.x;
    __shared__ float red[256];
    __shared__ float pool[240];
    float c = 0.f;
    for (int l = t; l < LP_; l += 256) c += (mask[b * LP_ + l] == 0.f) ? 1.f : 0.f;
    red[t] = c;
    __syncthreads();
    for (int off = 128; off > 0; off >>= 1) {
        if (t < off) red[t] += red[t + off];
        __syncthreads();
    }
    float inv = 1.f / red[0];
    if (t < D_) {
        float s = 0.f;
        #pragma unroll
        for (int sl = 0; sl < 9; sl++) s += partial[((size_t)b * 9 + sl) * D_ + t];
        pool[t] = s * inv;
    }
    __syncthreads();
    if (t < NC_) {
        float s = bias[t];
        for (int kk = 0; kk < D_; kk++) s += pool[kk] * W[(size_t)kk * NC_ + t];
        out[b * NC_ + t] = s;
    }
}

extern "C" void kernel_launch(void* const* d_in, const int* in_sizes, int n_in,
                              void* d_out, int out_size, void* d_ws, size_t ws_size,
                              hipStream_t stream) {
    const float* x        = (const float*)d_in[0];
    const float* pos      = (const float*)d_in[1];
    const float* cls      = (const float*)d_in[2];
    const float* e_W1     = (const float*)d_in[3];
    const float* e_b1     = (const float*)d_in[4];
    const float* e_g1     = (const float*)d_in[5];
    const float* e_bn1    = (const float*)d_in[6];
    const float* e_W2     = (const float*)d_in[7];
    const float* e_b2     = (const float*)d_in[8];
    const float* e_g2     = (const float*)d_in[9];
    const float* e_bn2    = (const float*)d_in[10];
    const float* ln1_g    = (const float*)d_in[11];
    const float* ln1_b    = (const float*)d_in[12];
    const float* Wq       = (const float*)d_in[13];
    const float* bq       = (const float*)d_in[14];
    const float* Wk       = (const float*)d_in[15];
    const float* bk       = (const float*)d_in[16];
    const float* Wv       = (const float*)d_in[17];
    const float* bv       = (const float*)d_in[18];
    const float* Wo       = (const float*)d_in[19];
    const float* bo       = (const float*)d_in[20];
    const float* ln2_g    = (const float*)d_in[21];
    const float* ln2_b    = (const float*)d_in[22];
    const float* W1       = (const float*)d_in[23];
    const float* b1       = (const float*)d_in[24];
    const float* W2       = (const float*)d_in[25];
    const float* b2       = (const float*)d_in[26];
    const float* logit_W  = (const float*)d_in[27];
    const float* logit_b  = (const float*)d_in[28];
    float* out = (float*)d_out;

    const size_t TOK  = (size_t)B_ * LP_;            // 8224
    const size_t TOKP = 8320;                        // padded to 65*128
    const size_t HN   = TOK * D_;
    const size_t QN   = (size_t)B_ * H_ * LP_ * 16;  // 2,105,344

    char* wsb = (char*)d_ws;
    size_t cur = 0;
    auto take = [&](size_t bytes) { void* p = wsb + cur; cur += (bytes + 15) & ~15ULL; return p; };
    float* mask = (float*)take(8224 * 4);
    float* h    = (float*)take(HN * 4);
    float* b720 = (float*)take(NB_ * 720 * 4);
    float* part = (float*)take((size_t)B_ * 9 * D_ * 4);
    void* regionA = take((size_t)8192 * 480 * 4);
    float* tmp1 = (float*)regionA;
    void* regionB = take(TOKP * 256 * 2 * 2);
    float* y32 = (float*)regionB;
    unsigned short* ybf = (unsigned short*)regionB;
    unsigned short* obf = ybf + TOKP * 256;
    unsigned short* xbf  = (unsigned short*)take((size_t)8192 * 192 * 2);
    unsigned short* We1  = (unsigned short*)take((size_t)512 * 192 * 2);
    unsigned short* We2  = (unsigned short*)take((size_t)256 * 480 * 2);
    unsigned short* Wqkv = (unsigned short*)take((size_t)NB_ * 768 * 256 * 2);
    unsigned short* WoT  = (unsigned short*)take((size_t)NB_ * 256 * 256 * 2);
    unsigned short* W1T  = (unsigned short*)take((size_t)NB_ * 512 * 256 * 2);
    unsigned short* W2T  = (unsigned short*)take((size_t)NB_ * 256 * 480 * 2);
    unsigned short* qp = (unsigned short*)take(QN * 3 * 2 + 16 * 16 * 2);
    unsigned short* kp = qp + QN;
    unsigned short* vp = kp + QN;
    unsigned short* t480bf = qp;   // aliases qp/kp, dead before embed_finish

    const int BS = 256;

    // prep (2 dispatches)
    prep_misc<<<8192 + NB_ + 129, 64, 0, stream>>>(x, xbf, bq, bk, bv, b720, mask);
    prep_weights<<<dim3(8, 38), BS, 0, stream>>>(e_W1, e_W2, Wq, Wk, Wv, Wo, W1, W2,
                                                 We1, We2, Wqkv, WoT, W1T, W2T);

    // embed (gemm2: z=1 plain write)
    gemm_mfma<<<dim3(64, 8), BS, 0, stream>>>(xbf, We1, e_b1, tmp1, nullptr,
                                              nullptr, nullptr, nullptr,
                                              8192, 480, 192, 480, 0);
    ln480<<<2048, BS, 0, stream>>>(tmp1, t480bf, e_g1, e_bn1);
    gemm_mfma<<<dim3(64, 4), BS, 0, stream>>>(t480bf, We2, e_b2, y32, nullptr,
                                              nullptr, nullptr, nullptr,
                                              8192, 240, 480, 240, 0);
    embed_finish<<<(int)(TOK / 4), BS, 0, stream>>>(y32, mask, e_g2, e_bn2, pos, cls,
                                                    ln1_g, ln1_b, h, ybf, qp, kp, vp);

    for (int i = 0; i < NB_; i++) {
        gemm_mfma<<<dim3(65, 12), BS, 0, stream>>>(ybf, Wqkv + (size_t)i * 768 * 256,
                                                   b720 + i * 720, nullptr, nullptr,
                                                   qp, kp, vp,
                                                   (int)TOK, 720, 256, 0, 4);
        attn_mfma<<<dim3(H_, B_), BS, 0, stream>>>(qp, kp, vp, obf);
        // Wo gemm + residual + fused ln2 -> ybf (64-row tile)
        gemm_row_ln<<<129, BS, 0, stream>>>(obf, WoT + (size_t)i * 256 * 256,
                                            bo + i * D_, h, ybf,
                                            ln2_g + i * D_, ln2_b + i * D_,
                                            (int)TOK, 256, 1);
        // FFN1 + FFN2 + residual + fused ln1(i+1) in ONE kernel (dbuf)
        ffn_fused<<<257, BS, 0, stream>>>(ybf, W1T + (size_t)i * 512 * 256,
                                          b1 + i * HID_,
                                          W2T + (size_t)i * 256 * 480,
                                          b2 + i * D_, h, ybf,
                                          ln1_g + ((i + 1) % NB_) * D_,
                                          ln1_b + ((i + 1) % NB_) * D_,
                                          (i < NB_ - 1) ? 1 : 0);
    }

    pool_partial<<<dim3(B_, 9), BS, 0, stream>>>(h, mask, part);
    pool_logits<<<B_, BS, 0, stream>>>(part, mask, logit_W, logit_b, out);
}

// Round 13
// 652.855 us; speedup vs baseline: 1.1685x; 1.1685x over previous
//
#include <hip/hip_runtime.h>
#include <math.h>

#define B_  32
#define L_  256
#define PD_ 164
#define D_  240
#define H_  16
#define NB_ 6
#define NC_ 250
#define DK_ 15
#define HID_ 480
#define LP_ 257
#define KP_ 288            // keys padded to 9*32
#define SCALE_ 0.2581988897471611f   // 1/sqrt(15)
#define LOG2E_ 1.4426950408889634f

typedef __attribute__((ext_vector_type(8))) short bf16x8;
typedef __attribute__((ext_vector_type(8))) _Float16 f16x8;
typedef __attribute__((ext_vector_type(4))) float f32x4;

static __device__ inline unsigned short f2bf(float x) {
    unsigned u = __builtin_bit_cast(unsigned, x);
    u += 0x7FFFu + ((u >> 16) & 1u);     // RNE (finite values only)
    return (unsigned short)(u >> 16);
}
static __device__ inline unsigned short f2h(float x) {
    _Float16 h = (_Float16)x;
    return __builtin_bit_cast(unsigned short, h);
}

// async global->LDS, 16B per lane; lds dest must be wave-uniform base (+lane*16)
static __device__ inline void gl2lds16(const void* g, void* l) {
    __builtin_amdgcn_global_load_lds(
        (const __attribute__((address_space(1))) unsigned int*)g,
        (__attribute__((address_space(3))) unsigned int*)l, 16, 0, 0);
}

// --------- prep_misc: cvt_x (0..8191) + pack_bias (8192..8197) + mask --------
__global__ void prep_misc(const float* __restrict__ x, unsigned short* __restrict__ xbf,
                          const float* __restrict__ bq, const float* __restrict__ bk,
                          const float* __restrict__ bv, float* __restrict__ b720,
                          float* __restrict__ mask) {
    int u = blockIdx.x;
    if (u < 8192) {
        const float* src = x + (size_t)u * PD_;
        unsigned short* dst = xbf + (size_t)u * 192;
        for (int k = threadIdx.x; k < 192; k += 64)
            dst[k] = f2bf(k < PD_ ? src[k] : 0.f);
    } else if (u < 8192 + NB_) {
        int i = u - 8192;
        for (int n = threadIdx.x; n < 720; n += 64) {
            float v = (n < 240) ? bq[i * 240 + n]
                    : (n < 480) ? bk[i * 240 + n - 240]
                                : bv[i * 240 + n - 480];
            b720[i * 720 + n] = v;
        }
    } else {
        int idx = (u - 8192 - NB_) * 64 + threadIdx.x;
        if (idx >= B_ * LP_) return;
        int b = idx / LP_, l = idx % LP_;
        if (l == 0) { mask[idx] = 0.f; return; }
        const float4* xr = (const float4*)(x + ((size_t)b * L_ + (l - 1)) * PD_);
        float4 m4 = xr[0];
        #pragma unroll 8
        for (int j = 1; j < 41; j++) {            // 41*4 = 164 exactly
            float4 v = xr[j];
            m4.x = fmaxf(m4.x, v.x); m4.y = fmaxf(m4.y, v.y);
            m4.z = fmaxf(m4.z, v.z); m4.w = fmaxf(m4.w, v.w);
        }
        float mx = fmaxf(fmaxf(m4.x, m4.y), fmaxf(m4.z, m4.w));
        mask[idx] = (mx == 0.f) ? 1.f : 0.f;
    }
}

// --------- prep_weights: 38 pretranspose jobs, LDS-tiled (coalesced) ---------
__global__ __launch_bounds__(256)
void prep_weights(const float* __restrict__ e_W1, const float* __restrict__ e_W2,
                  const float* __restrict__ Wq, const float* __restrict__ Wk,
                  const float* __restrict__ Wv, const float* __restrict__ Wo,
                  const float* __restrict__ W1, const float* __restrict__ W2,
                  unsigned short* __restrict__ We1, unsigned short* __restrict__ We2,
                  unsigned short* __restrict__ Wqkv, unsigned short* __restrict__ WoT,
                  unsigned short* __restrict__ W1T, unsigned short* __restrict__ W2T) {
    int job = blockIdx.y;
    const float* src; unsigned short* dst; int K, N, Kpad;
    if (job == 0)      { src = e_W1; dst = We1; K = PD_; N = 480; Kpad = 192; }
    else if (job == 1) { src = e_W2; dst = We2; K = 480; N = 240; Kpad = 480; }
    else {
        int i = (job - 2) % 6, w = (job - 2) / 6;
        if (w == 0)      { src = Wq + (size_t)i*240*240; dst = Wqkv + (size_t)i*768*256;           K=240; N=240; Kpad=256; }
        else if (w == 1) { src = Wk + (size_t)i*240*240; dst = Wqkv + (size_t)i*768*256 + 240*256; K=240; N=240; Kpad=256; }
        else if (w == 2) { src = Wv + (size_t)i*240*240; dst = Wqkv + (size_t)i*768*256 + 480*256; K=240; N=240; Kpad=256; }
        else if (w == 3) { src = Wo + (size_t)i*240*240; dst = WoT + (size_t)i*256*256;            K=240; N=256; Kpad=256; }
        else if (w == 4) { src = W1 + (size_t)i*240*480; dst = W1T + (size_t)i*512*256;            K=240; N=480; Kpad=256; }
        else             { src = W2 + (size_t)i*480*240; dst = W2T + (size_t)i*256*480;            K=480; N=256; Kpad=480; }
    }
    int n0 = blockIdx.x * 64;
    if (n0 >= N) return;
    int realN = (N == 256) ? 240 : N;
    __shared__ float tile[64][65];
    const int tid = threadIdx.x;
    const int lrow = tid >> 4;          // 0..15
    const int lcol = (tid & 15) * 4;    // 0..60
    const int wn   = tid >> 2;          // 0..63
    const int wq   = tid & 3;           // k-quarter
    for (int k0 = 0; k0 < Kpad; k0 += 64) {
        #pragma unroll
        for (int r4 = 0; r4 < 4; r4++) {
            int row = k0 + r4 * 16 + lrow;
            float4 v = {0.f, 0.f, 0.f, 0.f};
            if (row < K && n0 + lcol < realN)
                v = *(const float4*)(src + (size_t)row * realN + n0 + lcol);
            tile[r4 * 16 + lrow][lcol]     = v.x;
            tile[r4 * 16 + lrow][lcol + 1] = v.y;
            tile[r4 * 16 + lrow][lcol + 2] = v.z;
            tile[r4 * 16 + lrow][lcol + 3] = v.w;
        }
        __syncthreads();
        int n = n0 + wn;
        int kbase = k0 + wq * 16;
        if (n < N && kbase < Kpad) {
            unsigned short tmp[16];
            #pragma unroll
            for (int kk = 0; kk < 16; kk++)
                tmp[kk] = f2bf(tile[wq * 16 + kk][wn]);
            *(uint4*)(dst + (size_t)n * Kpad + kbase)     = *(uint4*)&tmp[0];
            *(uint4*)(dst + (size_t)n * Kpad + kbase + 8) = *(uint4*)&tmp[8];
        }
        __syncthreads();
    }
}

// ---------------- MFMA GEMM: C = A[M,Kpad]bf16 @ Bt[N,Kpad]bf16 --------------
// tile 128x64, 4 waves (2x2), K-step 32, double-buffered LDS + counted vmcnt.
// Block->tile mapping is XCD-chunk swizzled (bijective) with y-fastest order.
// flags: 1 relu, 2 accumulate fp32 C, 4 QKV-packed epilogue, 8 bf16 out
__global__ __launch_bounds__(256)
void gemm_mfma(const unsigned short* __restrict__ A,
               const unsigned short* __restrict__ Bt,
               const float* __restrict__ bias,
               float* __restrict__ C, unsigned short* __restrict__ Cbf,
               unsigned short* __restrict__ qp, unsigned short* __restrict__ kp,
               unsigned short* __restrict__ vp,
               int M, int N, int Kpad, int Cstride, int flags)
{
    __shared__ __align__(16) unsigned short As[2][128 * 32];   // 16 KB
    __shared__ __align__(16) unsigned short Bs[2][64 * 32];    // 8 KB
    const int tid = threadIdx.x;
    // ---- XCD-chunked swizzle: hw id c=flat%8 owns contiguous work chunk ----
    const int gx = gridDim.x, gy = gridDim.y;
    const int flat = blockIdx.x + gx * blockIdx.y;
    const int total = gx * gy;
    const int q8 = total >> 3, r8 = total & 7;
    const int cx = flat & 7, kx = flat >> 3;
    const int w = (cx < r8) ? (cx * (q8 + 1) + kx)
                            : (r8 * (q8 + 1) + (cx - r8) * q8 + kx);
    const int bmx = w / gy;            // x-tile (shares A across its y's)
    const int bny = w - bmx * gy;      // y-tile (y-fastest in work order)
    const int bm = bmx * 128;
    const int bn = bny * 64;
    const int zs = gridDim.z, zi = blockIdx.z;
    const int wave = tid >> 6, lane = tid & 63;
    const int wm = (wave & 1) * 64, wn = (wave >> 1) * 32;
    const int lq = lane >> 4, lr = lane & 15;

    f32x4 acc[4][2];
    #pragma unroll
    for (int i = 0; i < 4; i++)
        #pragma unroll
        for (int j = 0; j < 2; j++) acc[i][j] = (f32x4){0.f, 0.f, 0.f, 0.f};

    const int srow = lane >> 2;            // 0..15
    const int schk = (lane & 3) << 3;      // 0,8,16,24
    const int nkt = Kpad >> 5;
    const int kt0 = (nkt * zi) / zs;
    const int kt1 = (nkt * (zi + 1)) / zs;

    const unsigned short* ga0 = A + (size_t)(bm + wave * 32 + srow) * Kpad + schk + kt0 * 32;
    const unsigned short* ga1 = A + (size_t)(bm + wave * 32 + 16 + srow) * Kpad + schk + kt0 * 32;
    const unsigned short* gb  = Bt + (size_t)(bn + wave * 16 + srow) * Kpad + schk + kt0 * 32;
    char* sa = (char*)As + wave * 2048;    // per-wave slice of buffer 0
    char* sb = (char*)Bs + wave * 1024;

    #define STAGE_(bu)  do {                       \
        gl2lds16(ga0, sa + (bu) * 8192);           \
        gl2lds16(ga1, sa + (bu) * 8192 + 1024);    \
        gl2lds16(gb,  sb + (bu) * 4096);           \
        ga0 += 32; ga1 += 32; gb += 32;            \
    } while (0)

    STAGE_(0);                                  // prologue: tile kt0 -> buf 0
    int cur = 0;
    for (int kt = kt0; kt < kt1; kt++) {
        if (kt + 1 < kt1) {
            STAGE_(cur ^ 1);                    // prefetch next tile
            asm volatile("s_waitcnt vmcnt(3)" ::: "memory");   // current tile done
        } else {
            asm volatile("s_waitcnt vmcnt(0)" ::: "memory");
        }
        asm volatile("s_barrier" ::: "memory"); // all waves' stage of buf[cur] done
        const unsigned short* Asc = (const unsigned short*)((const char*)As + cur * 8192);
        const unsigned short* Bsc = (const unsigned short*)((const char*)Bs + cur * 4096);
        bf16x8 af[4], bfr[2];
        #pragma unroll
        for (int i = 0; i < 4; i++)
            af[i] = *(const bf16x8*)&Asc[(wm + i * 16 + lr) * 32 + lq * 8];
        #pragma unroll
        for (int j = 0; j < 2; j++)
            bfr[j] = *(const bf16x8*)&Bsc[(wn + j * 16 + lr) * 32 + lq * 8];
        #pragma unroll
        for (int i = 0; i < 4; i++)
            #pragma unroll
            for (int j = 0; j < 2; j++)
                acc[i][j] = __builtin_amdgcn_mfma_f32_16x16x32_bf16(af[i], bfr[j], acc[i][j], 0, 0, 0);
        asm volatile("s_barrier" ::: "memory"); // all waves done reading buf[cur]
        cur ^= 1;
    }
    #undef STAGE_

    if (flags & 4) {                       // QKV packed epilogue (N=720)
        #pragma unroll
        for (int j = 0; j < 2; j++) {
            int n = bn + wn + j * 16 + lr;
            if (n >= N) continue;
            int which = n / 240;
            int rem = n - which * 240;
            int hh = rem / 15;
            int c = rem - hh * 15;
            unsigned short* dst = (which == 0) ? qp : (which == 1) ? kp : vp;
            float bias_n = bias[n];
            float mult = (which == 0) ? (SCALE_ * LOG2E_) : 1.f;
            #pragma unroll
            for (int i = 0; i < 4; i++)
                #pragma unroll
                for (int r = 0; r < 4; r++) {
                    int m = bm + wm + i * 16 + lq * 4 + r;
                    if (m >= M) continue;
                    float s = (acc[i][j][r] + bias_n) * mult;
                    int b = m / LP_, l = m - b * LP_;
                    unsigned short bits = (which == 2) ? f2h(s) : f2bf(s);
                    dst[(((size_t)b * H_ + hh) * LP_ + l) * 16 + c] = bits;
                }
        }
    } else if (flags & 8) {                // bf16 output
        #pragma unroll
        for (int i = 0; i < 4; i++)
            #pragma unroll
            for (int j = 0; j < 2; j++) {
                int n = bn + wn + j * 16 + lr;
                if (n >= N) continue;
                float bias_n = bias ? bias[n] : 0.f;
                #pragma unroll
                for (int r = 0; r < 4; r++) {
                    int m = bm + wm + i * 16 + lq * 4 + r;
                    if (m >= M) continue;
                    float s = acc[i][j][r] + bias_n;
                    if (flags & 1) s = fmaxf(s, 0.f);
                    Cbf[(size_t)m * Cstride + n] = f2bf(s);
                }
            }
    } else {                               // fp32 output (optionally accumulate)
        #pragma unroll
        for (int i = 0; i < 4; i++)
            #pragma unroll
            for (int j = 0; j < 2; j++) {
                int n = bn + wn + j * 16 + lr;
                if (n >= N) continue;
                float bias_n = (bias && zi == 0) ? bias[n] : 0.f;
                #pragma unroll
                for (int r = 0; r < 4; r++) {
                    int m = bm + wm + i * 16 + lq * 4 + r;
                    if (m >= M) continue;
                    float s = acc[i][j][r] + bias_n;
                    if (flags & 1) s = fmaxf(s, 0.f);
                    size_t off = (size_t)m * Cstride + n;
                    if (flags & 2) {
                        if (zs > 1) atomicAdd(&C[off], s);
                        else C[off] += s;
                    } else C[off] = s;
                }
            }
    }
}

// -------- gemm_row_ln: full-row tile 64x240 (N padded 256), one block per
// 64 rows, 4 waves x 16 rows x full width, acc[16]. Epilogue:
// v = acc + bias + h (residual), h = v, in-register row-LN (shfl over the
// 16 lr-lanes that share a row: col=lr, row=lq*4+r), ybf = LN(v) bf16.
// flags: 1 = write ybf (LN output); else h-update only.
__global__ __launch_bounds__(256)
void gemm_row_ln(const unsigned short* __restrict__ A,
                 const unsigned short* __restrict__ Bt,
                 const float* __restrict__ bias,
                 float* __restrict__ h, unsigned short* __restrict__ ybf,
                 const float* __restrict__ lng, const float* __restrict__ lnb,
                 int M, int Kpad, int flags)
{
    __shared__ __align__(16) unsigned short As[2][64 * 32];    // 8 KB
    __shared__ __align__(16) unsigned short Bs[2][256 * 32];   // 32 KB
    const int tid = threadIdx.x;
    const int bm = blockIdx.x * 64;
    const int wave = tid >> 6, lane = tid & 63;
    const int wm = wave * 16;
    const int lq = lane >> 4, lr = lane & 15;
    const int srow = lane >> 2, schk = (lane & 3) << 3;
    const int nkt = Kpad >> 5;

    f32x4 acc[16];
    #pragma unroll
    for (int j = 0; j < 16; j++) acc[j] = (f32x4){0.f, 0.f, 0.f, 0.f};

    const unsigned short* ga0 = A + (size_t)(bm + wm + srow) * Kpad + schk;
    const unsigned short* gb0 = Bt + (size_t)(wave * 64 + srow) * Kpad + schk;
    char* sa = (char*)As + wave * 1024;
    char* sb = (char*)Bs + wave * 4096;

    #define STAGE_(bu)  do {                                      \
        gl2lds16(ga0, sa + (bu) * 4096);                          \
        gl2lds16(gb0,                   sb + (bu) * 16384);       \
        gl2lds16(gb0 + (size_t)16*Kpad, sb + (bu) * 16384 + 1024);\
        gl2lds16(gb0 + (size_t)32*Kpad, sb + (bu) * 16384 + 2048);\
        gl2lds16(gb0 + (size_t)48*Kpad, sb + (bu) * 16384 + 3072);\
        ga0 += 32; gb0 += 32;                                     \
    } while (0)

    STAGE_(0);
    int cur = 0;
    for (int kt = 0; kt < nkt; kt++) {
        if (kt + 1 < nkt) {
            STAGE_(cur ^ 1);
            asm volatile("s_waitcnt vmcnt(5)" ::: "memory");
        } else {
            asm volatile("s_waitcnt vmcnt(0)" ::: "memory");
        }
        asm volatile("s_barrier" ::: "memory");
        const unsigned short* Asc = (const unsigned short*)((const char*)As + cur * 4096);
        const unsigned short* Bsc = (const unsigned short*)((const char*)Bs + cur * 16384);
        bf16x8 af = *(const bf16x8*)&Asc[(wm + lr) * 32 + lq * 8];
        #pragma unroll
        for (int j = 0; j < 16; j++) {
            bf16x8 bf = *(const bf16x8*)&Bsc[(j * 16 + lr) * 32 + lq * 8];
            acc[j] = __builtin_amdgcn_mfma_f32_16x16x32_bf16(af, bf, acc[j], 0, 0, 0);
        }
        asm volatile("s_barrier" ::: "memory");
        cur ^= 1;
    }
    #undef STAGE_

    // ---- epilogue: residual + h write + in-register row-LN -> ybf ----
    float biasj[15], gj[15], bj[15];
    #pragma unroll
    for (int j = 0; j < 15; j++) {
        int n = j * 16 + lr;
        biasj[j] = bias[n];
        if (flags & 1) { gj[j] = lng[n]; bj[j] = lnb[n]; }
    }
    #pragma unroll
    for (int r = 0; r < 4; r++) {
        const int row = bm + wm + lq * 4 + r;
        if (row >= M) continue;          // uniform across the 16 lr-lanes
        float v[15];
        float s = 0.f;
        #pragma unroll
        for (int j = 0; j < 15; j++) {
            v[j] = acc[j][r] + biasj[j] + h[(size_t)row * 240 + j * 16 + lr];
            s += v[j];
        }
        s += __shfl_xor(s, 1); s += __shfl_xor(s, 2);
        s += __shfl_xor(s, 4); s += __shfl_xor(s, 8);
        #pragma unroll
        for (int j = 0; j < 15; j++)
            h[(size_t)row * 240 + j * 16 + lr] = v[j];
        if (flags & 1) {
            const float mean = s * (1.f / 240.f);
            float q = 0.f;
            #pragma unroll
            for (int j = 0; j < 15; j++) { float d = v[j] - mean; q += d * d; }
            q += __shfl_xor(q, 1); q += __shfl_xor(q, 2);
            q += __shfl_xor(q, 4); q += __shfl_xor(q, 8);
            const float rs = rsqrtf(q * (1.f / 240.f) + 1e-5f);
            #pragma unroll
            for (int j = 0; j < 15; j++)
                ybf[(size_t)row * 256 + j * 16 + lr] =
                    f2bf((v[j] - mean) * rs * gj[j] + bj[j]);
            ybf[(size_t)row * 256 + 240 + lr] = 0;   // pad cols
        }
    }
}

// -------- ffn_fused: per block 32 rows (257 blocks = 8224 exactly).
// Phase 1: t = relu(ybf[32x256] @ W1T^T + b1) -> LDS bf16 [32][488].
//   DOUBLE-buffered staging + counted vmcnt; Tl ALIASES B1 buffer 0 (written
//   only after phase-1's final barrier) so total LDS = 68 KB -> 2 blocks/CU.
// Phase 2: out = t @ W2T^T (K=480, 15 steps); waves 0,1 compute (acc2[15]);
//   B2 double-buffered inside B1 buffer 1's 32 KB.
//   Epilogue = residual + h + row-LN -> ybf (flags&1), same as gemm_row_ln.
__global__ __launch_bounds__(256)
void ffn_fused(const unsigned short* __restrict__ ybf_in,
               const unsigned short* __restrict__ W1t,
               const float* __restrict__ b1,
               const unsigned short* __restrict__ W2t,
               const float* __restrict__ b2,
               float* __restrict__ h, unsigned short* __restrict__ ybf,
               const float* __restrict__ lng, const float* __restrict__ lnb,
               int flags)
{
    __shared__ __align__(16) char S_[69632];   // 68 KB arena -> 2 blocks/CU
    // layout: [0,4K) Ad dbuf [2][2KB]; [4K,36K) B1 buf0 (aliased by Tl);
    //         [36K,68K) B1 buf1 (phase2: B2 dbuf [2][16KB])
    unsigned short* Tl = (unsigned short*)(S_ + 4096);   // [32][488] = 31.2 KB
    const int tid = threadIdx.x;
    const int bm = blockIdx.x * 32;
    const int wave = tid >> 6, lane = tid & 63;
    const int rg = wave >> 1, ch = wave & 1;   // row-group, col-half
    const int lq = lane >> 4, lr = lane & 15;
    const int srow = lane >> 2, schk = (lane & 3) << 3;

    // ---------------- phase 1: t = relu(ybf @ W1T + b1) ----------------
    f32x4 acc1[15];
    #pragma unroll
    for (int j = 0; j < 15; j++) acc1[j] = (f32x4){0.f, 0.f, 0.f, 0.f};

    const unsigned short* gaA = ybf_in + (size_t)(bm + wave * 16 + srow) * 256 + schk;
    const unsigned short* gb1 = W1t + (size_t)(wave * 128 + srow) * 256 + schk;

    #define STAGE1_(bu)  do {                                                  \
        if (wave < 2) gl2lds16(gaA, S_ + (bu) * 2048 + wave * 1024);           \
        _Pragma("unroll")                                                      \
        for (int s = 0; s < 8; s++)                                            \
            gl2lds16(gb1 + (size_t)s * 16 * 256,                               \
                     S_ + 4096 + (bu) * 32768 + (wave * 8 + s) * 1024);        \
        gaA += 32; gb1 += 32;                                                  \
    } while (0)

    STAGE1_(0);
    int cur = 0;
    for (int kt = 0; kt < 8; kt++) {
        if (kt + 1 < 8) {
            STAGE1_(cur ^ 1);
            if (wave < 2) { asm volatile("s_waitcnt vmcnt(9)" ::: "memory"); }
            else          { asm volatile("s_waitcnt vmcnt(8)" ::: "memory"); }
        } else {
            asm volatile("s_waitcnt vmcnt(0)" ::: "memory");
        }
        asm volatile("s_barrier" ::: "memory");
        const unsigned short* Adc = (const unsigned short*)(S_ + cur * 2048);
        const unsigned short* B1c = (const unsigned short*)(S_ + 4096 + cur * 32768);
        bf16x8 af = *(const bf16x8*)&Adc[(rg * 16 + lr) * 32 + lq * 8];
        #pragma unroll
        for (int j = 0; j < 15; j++) {
            bf16x8 bf = *(const bf16x8*)&B1c[(ch * 240 + j * 16 + lr) * 32 + lq * 8];
            acc1[j] = __builtin_amdgcn_mfma_f32_16x16x32_bf16(af, bf, acc1[j], 0, 0, 0);
        }
        asm volatile("s_barrier" ::: "memory");
        cur ^= 1;
    }
    #undef STAGE1_

    // write t = relu(acc1 + b1) to LDS bf16 [32][488] (aliases B1 buf0;
    // safe: all waves are past their last B1 reads after the final barrier)
    #pragma unroll
    for (int j = 0; j < 15; j++) {
        const int col = ch * 240 + j * 16 + lr;
        const float bb = b1[col];
        #pragma unroll
        for (int r = 0; r < 4; r++) {
            const int row = rg * 16 + lq * 4 + r;
            Tl[row * 488 + col] = f2bf(fmaxf(acc1[j][r] + bb, 0.f));
        }
    }
    __syncthreads();   // t complete; B1 buf1 region now reusable as B2 dbuf

    // ---------------- phase 2: out = t @ W2T + b2, residual + LN --------
    f32x4 acc2[15];
    #pragma unroll
    for (int j = 0; j < 15; j++) acc2[j] = (f32x4){0.f, 0.f, 0.f, 0.f};

    const unsigned short* gb2 = W2t + (size_t)(wave * 64 + srow) * 480 + schk;
    char* B2base = S_ + 4096 + 32768;          // [2][16KB] dbuf in B1 buf1

    #define STAGE2_(bu)  do {                                                  \
        _Pragma("unroll")                                                      \
        for (int s = 0; s < 4; s++)                                            \
            gl2lds16(gb2 + (size_t)s * 16 * 480,                               \
                     B2base + (bu) * 16384 + (wave * 4 + s) * 1024);           \
        gb2 += 32;                                                             \
    } while (0)

    STAGE2_(0);
    cur = 0;
    for (int kt = 0; kt < 15; kt++) {
        if (kt + 1 < 15) {
            STAGE2_(cur ^ 1);
            asm volatile("s_waitcnt vmcnt(4)" ::: "memory");
        } else {
            asm volatile("s_waitcnt vmcnt(0)" ::: "memory");
        }
        asm volatile("s_barrier" ::: "memory");
        if (wave < 2) {
            const unsigned short* B2c = (const unsigned short*)(B2base + cur * 16384);
            bf16x8 af = *(const bf16x8*)&Tl[(wave * 16 + lr) * 488 + kt * 32 + lq * 8];
            #pragma unroll
            for (int j = 0; j < 15; j++) {
                bf16x8 bf = *(const bf16x8*)&B2c[(j * 16 + lr) * 32 + lq * 8];
                acc2[j] = __builtin_amdgcn_mfma_f32_16x16x32_bf16(af, bf, acc2[j], 0, 0, 0);
            }
        }
        asm volatile("s_barrier" ::: "memory");
        cur ^= 1;
    }
    #undef STAGE2_

    if (wave >= 2) return;
    // epilogue: rows bm + wave*16 + lq*4 + r  (identical math to gemm_row_ln)
    float biasj[15], gj[15], bj[15];
    #pragma unroll
    for (int j = 0; j < 15; j++) {
        int n = j * 16 + lr;
        biasj[j] = b2[n];
        if (flags & 1) { gj[j] = lng[n]; bj[j] = lnb[n]; }
    }
    #pragma unroll
    for (int r = 0; r < 4; r++) {
        const int row = bm + wave * 16 + lq * 4 + r;
        float v[15];
        float s = 0.f;
        #pragma unroll
        for (int j = 0; j < 15; j++) {
            v[j] = acc2[j][r] + biasj[j] + h[(size_t)row * 240 + j * 16 + lr];
            s += v[j];
        }
        s += __shfl_xor(s, 1); s += __shfl_xor(s, 2);
        s += __shfl_xor(s, 4); s += __shfl_xor(s, 8);
        #pragma unroll
        for (int j = 0; j < 15; j++)
            h[(size_t)row * 240 + j * 16 + lr] = v[j];
        if (flags & 1) {
            const float mean = s * (1.f / 240.f);
            float q = 0.f;
            #pragma unroll
            for (int j = 0; j < 15; j++) { float d = v[j] - mean; q += d * d; }
            q += __shfl_xor(q, 1); q += __shfl_xor(q, 2);
            q += __shfl_xor(q, 4); q += __shfl_xor(q, 8);
            const float rs = rsqrtf(q * (1.f / 240.f) + 1e-5f);
            #pragma unroll
            for (int j = 0; j < 15; j++)
                ybf[(size_t)row * 256 + j * 16 + lr] =
                    f2bf((v[j] - mean) * rs * gj[j] + bj[j]);
            ybf[(size_t)row * 256 + 240 + lr] = 0;   // pad cols
        }
    }
}

// ------------- LN480+relu: wave-per-row, fp32 in -> bf16 out [rows][480] -----
__global__ __launch_bounds__(256)
void ln480(const float* __restrict__ in, unsigned short* __restrict__ out,
           const float* __restrict__ g, const float* __restrict__ bb) {
    const int row = blockIdx.x * 4 + (threadIdx.x >> 6);
    const int lane = threadIdx.x & 63;
    const float* x = in + (size_t)row * 480;
    float4 va = {0.f,0.f,0.f,0.f}, vb = {0.f,0.f,0.f,0.f};
    if (lane < 60) {
        va = *(const float4*)(x + lane * 8);
        vb = *(const float4*)(x + lane * 8 + 4);
    }
    float s = ((va.x + va.y) + (va.z + va.w)) + ((vb.x + vb.y) + (vb.z + vb.w));
    #pragma unroll
    for (int off = 32; off; off >>= 1) s += __shfl_xor(s, off);
    const float mean = s * (1.f / 480.f);
    float4 da, db;
    da.x = va.x - mean; da.y = va.y - mean; da.z = va.z - mean; da.w = va.w - mean;
    db.x = vb.x - mean; db.y = vb.y - mean; db.z = vb.z - mean; db.w = vb.w - mean;
    float vs = (lane < 60) ? ((da.x*da.x + da.y*da.y) + (da.z*da.z + da.w*da.w)) +
                             ((db.x*db.x + db.y*db.y) + (db.z*db.z + db.w*db.w)) : 0.f;
    #pragma unroll
    for (int off = 32; off; off >>= 1) vs += __shfl_xor(vs, off);
    const float rs = rsqrtf(vs * (1.f / 480.f) + 1e-5f);
    if (lane < 60) {
        float4 ga = *(const float4*)(g + lane * 8);
        float4 gb = *(const float4*)(g + lane * 8 + 4);
        float4 ba = *(const float4*)(bb + lane * 8);
        float4 b2 = *(const float4*)(bb + lane * 8 + 4);
        ushort4 oa, ob;
        oa.x = f2bf(fmaxf(da.x * rs * ga.x + ba.x, 0.f));
        oa.y = f2bf(fmaxf(da.y * rs * ga.y + ba.y, 0.f));
        oa.z = f2bf(fmaxf(da.z * rs * ga.z + ba.z, 0.f));
        oa.w = f2bf(fmaxf(da.w * rs * ga.w + ba.w, 0.f));
        ob.x = f2bf(fmaxf(db.x * rs * gb.x + b2.x, 0.f));
        ob.y = f2bf(fmaxf(db.y * rs * gb.y + b2.y, 0.f));
        ob.z = f2bf(fmaxf(db.z * rs * gb.z + b2.z, 0.f));
        ob.w = f2bf(fmaxf(db.w * rs * gb.w + b2.w, 0.f));
        *(ushort4*)(out + (size_t)row * 480 + lane * 8) = oa;
        *(ushort4*)(out + (size_t)row * 480 + lane * 8 + 4) = ob;
    }
}

// -------- embed finish: wave-per-row LN(g2)+relu+pos (cls for l==0),
// then layer-0 ln1 of the same row in-register -> ybf. lanes 60..62 also
// write q/k/v col-15 constants (replaces attn_init).
__global__ __launch_bounds__(256)
void embed_finish(const float* __restrict__ tmp, const float* __restrict__ mask,
                  const float* __restrict__ g, const float* __restrict__ bb,
                  const float* __restrict__ pos, const float* __restrict__ cls,
                  const float* __restrict__ l1g, const float* __restrict__ l1b,
                  float* __restrict__ h, unsigned short* __restrict__ ybf,
                  unsigned short* __restrict__ qp, unsigned short* __restrict__ kp,
                  unsigned short* __restrict__ vp) {
    const int row = blockIdx.x * 4 + (threadIdx.x >> 6);
    const int lane = threadIdx.x & 63;
    const int b = row / LP_, l = row - b * LP_;
    float* outr = h + (size_t)row * 240;

    if (lane >= 60 && lane <= 62) {
        unsigned short bits;
        unsigned short* dst;
        if (lane == 60) { bits = f2bf(LOG2E_); dst = qp; }
        else if (lane == 61) { bits = (mask[row] != 0.f) ? f2bf(-10000.f) : 0; dst = kp; }
        else { bits = f2h(1.f); dst = vp; }
        #pragma unroll
        for (int hh = 0; hh < H_; hh++)
            dst[(((size_t)b * H_ + hh) * LP_ + l) * 16 + 15] = bits;
    }

    float4 o = {0.f, 0.f, 0.f, 0.f};
    if (l == 0) {
        if (lane < 60) o = *(const float4*)(cls + lane * 4);
    } else {
        const float* x = tmp + ((size_t)b * L_ + (l - 1)) * 240;
        float4 v = {0.f, 0.f, 0.f, 0.f};
        if (lane < 60) v = *(const float4*)(x + lane * 4);
        float s = (v.x + v.y) + (v.z + v.w);
        #pragma unroll
        for (int off = 32; off; off >>= 1) s += __shfl_xor(s, off);
        const float mean = s * (1.f / 240.f);
        float4 d;
        d.x = v.x - mean; d.y = v.y - mean; d.z = v.z - mean; d.w = v.w - mean;
        float vs = (lane < 60) ? (d.x * d.x + d.y * d.y) + (d.z * d.z + d.w * d.w) : 0.f;
        #pragma unroll
        for (int off = 32; off; off >>= 1) vs += __shfl_xor(vs, off);
        const float rs = rsqrtf(vs * (1.f / 240.f) + 1e-5f);
        if (lane < 60) {
            float4 g4 = *(const float4*)(g + lane * 4);
            float4 b4 = *(const float4*)(bb + lane * 4);
            float4 p4 = *(const float4*)(pos + (size_t)(l - 1) * 240 + lane * 4);
            o.x = fmaxf(d.x * rs * g4.x + b4.x, 0.f) + p4.x;
            o.y = fmaxf(d.y * rs * g4.y + b4.y, 0.f) + p4.y;
            o.z = fmaxf(d.z * rs * g4.z + b4.z, 0.f) + p4.z;
            o.w = fmaxf(d.w * rs * g4.w + b4.w, 0.f) + p4.w;
        }
    }
    if (lane < 60) *(float4*)(outr + lane * 4) = o;

    // ---- layer-0 ln1 of this row (value already in registers) ----
    float s1 = (o.x + o.y) + (o.z + o.w);
    #pragma unroll
    for (int off = 32; off; off >>= 1) s1 += __shfl_xor(s1, off);
    const float mean1 = s1 * (1.f / 240.f);
    float4 d1;
    d1.x = o.x - mean1; d1.y = o.y - mean1; d1.z = o.z - mean1; d1.w = o.w - mean1;
    float vs1 = (lane < 60) ? (d1.x * d1.x + d1.y * d1.y) + (d1.z * d1.z + d1.w * d1.w) : 0.f;
    #pragma unroll
    for (int off = 32; off; off >>= 1) vs1 += __shfl_xor(vs1, off);
    const float rs1 = rsqrtf(vs1 * (1.f / 240.f) + 1e-5f);
    ushort4 o4 = {0, 0, 0, 0};
    if (lane < 60) {
        float4 g4 = *(const float4*)(l1g + lane * 4);
        float4 b4 = *(const float4*)(l1b + lane * 4);
        o4.x = f2bf(d1.x * rs1 * g4.x + b4.x);
        o4.y = f2bf(d1.y * rs1 * g4.y + b4.y);
        o4.z = f2bf(d1.z * rs1 * g4.z + b4.z);
        o4.w = f2bf(d1.w * rs1 * g4.w + b4.w);
    }
    *(ushort4*)(ybf + (size_t)row * 256 + lane * 4) = o4;
}

// ---------------- MFMA flash attention: block per (b,h), 4 waves -------------
__global__ __launch_bounds__(256)
void attn_mfma(const unsigned short* __restrict__ qp, const unsigned short* __restrict__ kp,
               const unsigned short* __restrict__ vp, unsigned short* __restrict__ obf)
{
    __shared__ __align__(16) unsigned short Kl[KP_ * 24];    // 13.5 KB
    __shared__ __align__(16) unsigned short Vt[16 * 296];    // 9.25 KB  V^T f16
    __shared__ __align__(16) unsigned short Pl[4][16 * 296]; // 37 KB    P f16 per wave
    const int hh = blockIdx.x, b = blockIdx.y;
    const int tid = threadIdx.x;
    const int wave = tid >> 6, lane = tid & 63;
    const int lq = lane >> 4, lr = lane & 15;
    const size_t base = ((size_t)b * H_ + hh) * LP_ * 16;

    for (int key = tid; key < KP_; key += 256) {
        uint4 z = {0u, 0u, 0u, 0u};
        uint4 k0 = z, k1 = z, v0 = z, v1 = z;
        if (key < LP_) {
            k0 = *(const uint4*)(kp + base + (size_t)key * 16);
            k1 = *(const uint4*)(kp + base + (size_t)key * 16 + 8);
            v0 = *(const uint4*)(vp + base + (size_t)key * 16);
            v1 = *(const uint4*)(vp + base + (size_t)key * 16 + 8);
        } else {
            k1.w = 0xC61C0000u;            // elem15 = bf16(-10000) sentinel
        }
        *(uint4*)&Kl[key * 24] = k0;
        *(uint4*)&Kl[key * 24 + 8] = k1;
        unsigned short vs[8];
        *(uint4*)vs = v0;
        #pragma unroll
        for (int d = 0; d < 8; d++) Vt[d * 296 + key] = vs[d];
        *(uint4*)vs = v1;
        #pragma unroll
        for (int d = 0; d < 8; d++) Vt[(d + 8) * 296 + key] = vs[d];
    }
    __syncthreads();

    unsigned short* Pw = &Pl[wave][0];
    {   // keys 272..287 are pure padding every qt: zero their P once per wave
        int r = lane >> 2, c0 = 272 + (lane & 3) * 4;
        ushort4 z4 = {0, 0, 0, 0};
        *(ushort4*)&Pw[r * 296 + c0] = z4;
    }
    for (int qt = wave; qt < 17; qt += 4) {
        const int qrow = qt * 16 + lr;
        bf16x8 aq = {0, 0, 0, 0, 0, 0, 0, 0};
        if (lq < 2)
            aq = *(const bf16x8*)(qp + base + (size_t)qrow * 16 + lq * 8);
        for (int kt = 0; kt < 17; kt++) {      // kt=17 tile is all padding: skipped
            bf16x8 bk = {0, 0, 0, 0, 0, 0, 0, 0};
            if (lq < 2)
                bk = *(const bf16x8*)&Kl[(kt * 16 + lr) * 24 + lq * 8];
            f32x4 sacc = {0.f, 0.f, 0.f, 0.f};
            sacc = __builtin_amdgcn_mfma_f32_16x16x32_bf16(aq, bk, sacc, 0, 0, 0);
            #pragma unroll
            for (int r = 0; r < 4; r++)
                Pw[(lq * 4 + r) * 296 + kt * 16 + lr] = f2h(exp2f(sacc[r]));
        }
        asm volatile("s_waitcnt lgkmcnt(0)" ::: "memory");
        f32x4 o = {0.f, 0.f, 0.f, 0.f};
        __builtin_amdgcn_s_setprio(1);
        #pragma unroll
        for (int ks = 0; ks < 9; ks++) {
            f16x8 ap = *(const f16x8*)&Pw[lr * 296 + ks * 32 + lq * 8];
            f16x8 bv = *(const f16x8*)&Vt[lr * 296 + ks * 32 + lq * 8];
            o = __builtin_amdgcn_mfma_f32_16x16x32_f16(ap, bv, o, 0, 0, 0);
        }
        __builtin_amdgcn_s_setprio(0);
        asm volatile("s_waitcnt lgkmcnt(0)" ::: "memory");
        #pragma unroll
        for (int r = 0; r < 4; r++) {
            float denom = __shfl(o[r], lane | 15);
            int q = qt * 16 + lq * 4 + r;
            if (q < LP_ && lr < 15)
                obf[((size_t)b * LP_ + q) * 256 + hh * DK_ + lr] = f2bf(o[r] / denom);
        }
    }
    // zero pad cols 240..255 (once per row, by hh==0 block)
    if (hh == 0) {
        for (int q = tid; q < LP_; q += 256) {
            uint4 z = {0u, 0u, 0u, 0u};
            *(uint4*)(obf + ((size_t)b * LP_ + q) * 256 + 240) = z;
            *(uint4*)(obf + ((size_t)b * LP_ + q) * 256 + 248) = z;
        }
    }
}

// ---------------- masked mean pool (partial) ---------------------------------
__global__ void pool_partial(const float* __restrict__ h, const float* __restrict__ mask,
                             float* __restrict__ partial) {
    int b = blockIdx.x, slice = blockIdx.y;
    int d = threadIdx.x;
    if (d >= D_) return;
    float s = 0.f;
    int l0 = slice * 29;
    for (int i = 0; i < 29; i++) {
        int l = l0 + i;
        if (l < LP_ && mask[b * LP_ + l] == 0.f)
            s += h[((size_t)b * LP_ + l) * D_ + d];
    }
    partial[((size_t)b * 9 + slice) * D_ + d] = s;
}

// ---------------- pool finalize + logits -------------------------------------
__global__ __launch_bounds__(256)
void pool_logits(const float* __restrict__ partial, const float* __restrict__ mask,
                 const float* __restrict__ W, const float* __restrict__ bias,
                 float* __restrict__ out) {
    int b = blockIdx.x;
    int t = threadIdx.x;
    __shared__ float red[256];
    __shared__ float pool[240];
    float c = 0.f;
    for (int l = t; l < LP_; l += 256) c += (mask[b * LP_ + l] == 0.f) ? 1.f : 0.f;
    red[t] = c;
    __syncthreads();
    for (int off = 128; off > 0; off >>= 1) {
        if (t < off) red[t] += red[t + off];
        __syncthreads();
    }
    float inv = 1.f / red[0];
    if (t < D_) {
        float s = 0.f;
        #pragma unroll
        for (int sl = 0; sl < 9; sl++) s += partial[((size_t)b * 9 + sl) * D_ + t];
        pool[t] = s * inv;
    }
    __syncthreads();
    if (t < NC_) {
        float s = bias[t];
        for (int kk = 0; kk < D_; kk++) s += pool[kk] * W[(size_t)kk * NC_ + t];
        out[b * NC_ + t] = s;
    }
}

extern "C" void kernel_launch(void* const* d_in, const int* in_sizes, int n_in,
                              void* d_out, int out_size, void* d_ws, size_t ws_size,
                              hipStream_t stream) {
    const float* x        = (const float*)d_in[0];
    const float* pos      = (const float*)d_in[1];
    const float* cls      = (const float*)d_in[2];
    const float* e_W1     = (const float*)d_in[3];
    const float* e_b1     = (const float*)d_in[4];
    const float* e_g1     = (const float*)d_in[5];
    const float* e_bn1    = (const float*)d_in[6];
    const float* e_W2     = (const float*)d_in[7];
    const float* e_b2     = (const float*)d_in[8];
    const float* e_g2     = (const float*)d_in[9];
    const float* e_bn2    = (const float*)d_in[10];
    const float* ln1_g    = (const float*)d_in[11];
    const float* ln1_b    = (const float*)d_in[12];
    const float* Wq       = (const float*)d_in[13];
    const float* bq       = (const float*)d_in[14];
    const float* Wk       = (const float*)d_in[15];
    const float* bk       = (const float*)d_in[16];
    const float* Wv       = (const float*)d_in[17];
    const float* bv       = (const float*)d_in[18];
    const float* Wo       = (const float*)d_in[19];
    const float* bo       = (const float*)d_in[20];
    const float* ln2_g    = (const float*)d_in[21];
    const float* ln2_b    = (const float*)d_in[22];
    const float* W1       = (const float*)d_in[23];
    const float* b1       = (const float*)d_in[24];
    const float* W2       = (const float*)d_in[25];
    const float* b2       = (const float*)d_in[26];
    const float* logit_W  = (const float*)d_in[27];
    const float* logit_b  = (const float*)d_in[28];
    float* out = (float*)d_out;

    const size_t TOK  = (size_t)B_ * LP_;            // 8224
    const size_t TOKP = 8320;                        // padded to 65*128
    const size_t HN   = TOK * D_;
    const size_t QN   = (size_t)B_ * H_ * LP_ * 16;  // 2,105,344

    char* wsb = (char*)d_ws;
    size_t cur = 0;
    auto take = [&](size_t bytes) { void* p = wsb + cur; cur += (bytes + 15) & ~15ULL; return p; };
    float* mask = (float*)take(8224 * 4);
    float* h    = (float*)take(HN * 4);
    float* b720 = (float*)take(NB_ * 720 * 4);
    float* part = (float*)take((size_t)B_ * 9 * D_ * 4);
    void* regionA = take((size_t)8192 * 480 * 4);
    float* tmp1 = (float*)regionA;
    void* regionB = take(TOKP * 256 * 2 * 2);
    float* y32 = (float*)regionB;
    unsigned short* ybf = (unsigned short*)regionB;
    unsigned short* obf = ybf + TOKP * 256;
    unsigned short* xbf  = (unsigned short*)take((size_t)8192 * 192 * 2);
    unsigned short* We1  = (unsigned short*)take((size_t)512 * 192 * 2);
    unsigned short* We2  = (unsigned short*)take((size_t)256 * 480 * 2);
    unsigned short* Wqkv = (unsigned short*)take((size_t)NB_ * 768 * 256 * 2);
    unsigned short* WoT  = (unsigned short*)take((size_t)NB_ * 256 * 256 * 2);
    unsigned short* W1T  = (unsigned short*)take((size_t)NB_ * 512 * 256 * 2);
    unsigned short* W2T  = (unsigned short*)take((size_t)NB_ * 256 * 480 * 2);
    unsigned short* qp = (unsigned short*)take(QN * 3 * 2 + 16 * 16 * 2);
    unsigned short* kp = qp + QN;
    unsigned short* vp = kp + QN;
    unsigned short* t480bf = qp;   // aliases qp/kp, dead before embed_finish

    const int BS = 256;

    // prep (2 dispatches)
    prep_misc<<<8192 + NB_ + 129, 64, 0, stream>>>(x, xbf, bq, bk, bv, b720, mask);
    prep_weights<<<dim3(8, 38), BS, 0, stream>>>(e_W1, e_W2, Wq, Wk, Wv, Wo, W1, W2,
                                                 We1, We2, Wqkv, WoT, W1T, W2T);

    // embed (gemm2: z=1 plain write)
    gemm_mfma<<<dim3(64, 8), BS, 0, stream>>>(xbf, We1, e_b1, tmp1, nullptr,
                                              nullptr, nullptr, nullptr,
                                              8192, 480, 192, 480, 0);
    ln480<<<2048, BS, 0, stream>>>(tmp1, t480bf, e_g1, e_bn1);
    gemm_mfma<<<dim3(64, 4), BS, 0, stream>>>(t480bf, We2, e_b2, y32, nullptr,
                                              nullptr, nullptr, nullptr,
                                              8192, 240, 480, 240, 0);
    embed_finish<<<(int)(TOK / 4), BS, 0, stream>>>(y32, mask, e_g2, e_bn2, pos, cls,
                                                    ln1_g, ln1_b, h, ybf, qp, kp, vp);

    for (int i = 0; i < NB_; i++) {
        gemm_mfma<<<dim3(65, 12), BS, 0, stream>>>(ybf, Wqkv + (size_t)i * 768 * 256,
                                                   b720 + i * 720, nullptr, nullptr,
                                                   qp, kp, vp,
                                                   (int)TOK, 720, 256, 0, 4);
        attn_mfma<<<dim3(H_, B_), BS, 0, stream>>>(qp, kp, vp, obf);
        // Wo gemm + residual + fused ln2 -> ybf (64-row tile)
        gemm_row_ln<<<129, BS, 0, stream>>>(obf, WoT + (size_t)i * 256 * 256,
                                            bo + i * D_, h, ybf,
                                            ln2_g + i * D_, ln2_b + i * D_,
                                            (int)TOK, 256, 1);
        // FFN1 + FFN2 + residual + fused ln1(i+1) in ONE kernel (dbuf, 68KB)
        ffn_fused<<<257, BS, 0, stream>>>(ybf, W1T + (size_t)i * 512 * 256,
                                          b1 + i * HID_,
                                          W2T + (size_t)i * 256 * 480,
                                          b2 + i * D_, h, ybf,
                                          ln1_g + ((i + 1) % NB_) * D_,
                                          ln1_b + ((i + 1) % NB_) * D_,
                                          (i < NB_ - 1) ? 1 : 0);
    }

    pool_partial<<<dim3(B_, 9), BS, 0, stream>>>(h, mask, part);
    pool_logits<<<B_, BS, 0, stream>>>(part, mask, logit_W, logit_b, out);
}

// Round 14
// 648.841 us; speedup vs baseline: 1.1757x; 1.0062x over previous
//
#include <hip/hip_runtime.h>
#include <math.h>

#define B_  32
#define L_  256
#define PD_ 164
#define D_  240
#define H_  16
#define NB_ 6
#define NC_ 250
#define DK_ 15
#define HID_ 480
#define LP_ 257
#define KP_ 288            // keys padded to 9*32
#define SCALE_ 0.2581988897471611f   // 1/sqrt(15)
#define LOG2E_ 1.4426950408889634f

typedef __attribute__((ext_vector_type(8))) short bf16x8;
typedef __attribute__((ext_vector_type(8))) _Float16 f16x8;
typedef __attribute__((ext_vector_type(4))) float f32x4;

static __device__ inline unsigned short f2bf(float x) {
    unsigned u = __builtin_bit_cast(unsigned, x);
    u += 0x7FFFu + ((u >> 16) & 1u);     // RNE (finite values only)
    return (unsigned short)(u >> 16);
}
static __device__ inline unsigned short f2h(float x) {
    _Float16 h = (_Float16)x;
    return __builtin_bit_cast(unsigned short, h);
}

// async global->LDS, 16B per lane; lds dest must be wave-uniform base (+lane*16)
static __device__ inline void gl2lds16(const void* g, void* l) {
    __builtin_amdgcn_global_load_lds(
        (const __attribute__((address_space(1))) unsigned int*)g,
        (__attribute__((address_space(3))) unsigned int*)l, 16, 0, 0);
}

// --------- prep_misc: cvt_x (0..8191) + pack_bias (8192..8197) + mask --------
__global__ void prep_misc(const float* __restrict__ x, unsigned short* __restrict__ xbf,
                          const float* __restrict__ bq, const float* __restrict__ bk,
                          const float* __restrict__ bv, float* __restrict__ b720,
                          float* __restrict__ mask) {
    int u = blockIdx.x;
    if (u < 8192) {
        const float* src = x + (size_t)u * PD_;
        unsigned short* dst = xbf + (size_t)u * 192;
        for (int k = threadIdx.x; k < 192; k += 64)
            dst[k] = f2bf(k < PD_ ? src[k] : 0.f);
    } else if (u < 8192 + NB_) {
        int i = u - 8192;
        for (int n = threadIdx.x; n < 720; n += 64) {
            float v = (n < 240) ? bq[i * 240 + n]
                    : (n < 480) ? bk[i * 240 + n - 240]
                                : bv[i * 240 + n - 480];
            b720[i * 720 + n] = v;
        }
    } else {
        int idx = (u - 8192 - NB_) * 64 + threadIdx.x;
        if (idx >= B_ * LP_) return;
        int b = idx / LP_, l = idx % LP_;
        if (l == 0) { mask[idx] = 0.f; return; }
        const float4* xr = (const float4*)(x + ((size_t)b * L_ + (l - 1)) * PD_);
        float4 m4 = xr[0];
        #pragma unroll 8
        for (int j = 1; j < 41; j++) {            // 41*4 = 164 exactly
            float4 v = xr[j];
            m4.x = fmaxf(m4.x, v.x); m4.y = fmaxf(m4.y, v.y);
            m4.z = fmaxf(m4.z, v.z); m4.w = fmaxf(m4.w, v.w);
        }
        float mx = fmaxf(fmaxf(m4.x, m4.y), fmaxf(m4.z, m4.w));
        mask[idx] = (mx == 0.f) ? 1.f : 0.f;
    }
}

// --------- prep_weights: 38 pretranspose jobs, LDS-tiled (coalesced) ---------
__global__ __launch_bounds__(256)
void prep_weights(const float* __restrict__ e_W1, const float* __restrict__ e_W2,
                  const float* __restrict__ Wq, const float* __restrict__ Wk,
                  const float* __restrict__ Wv, const float* __restrict__ Wo,
                  const float* __restrict__ W1, const float* __restrict__ W2,
                  unsigned short* __restrict__ We1, unsigned short* __restrict__ We2,
                  unsigned short* __restrict__ Wqkv, unsigned short* __restrict__ WoT,
                  unsigned short* __restrict__ W1T, unsigned short* __restrict__ W2T) {
    int job = blockIdx.y;
    const float* src; unsigned short* dst; int K, N, Kpad;
    if (job == 0)      { src = e_W1; dst = We1; K = PD_; N = 480; Kpad = 192; }
    else if (job == 1) { src = e_W2; dst = We2; K = 480; N = 240; Kpad = 480; }
    else {
        int i = (job - 2) % 6, w = (job - 2) / 6;
        if (w == 0)      { src = Wq + (size_t)i*240*240; dst = Wqkv + (size_t)i*768*256;           K=240; N=240; Kpad=256; }
        else if (w == 1) { src = Wk + (size_t)i*240*240; dst = Wqkv + (size_t)i*768*256 + 240*256; K=240; N=240; Kpad=256; }
        else if (w == 2) { src = Wv + (size_t)i*240*240; dst = Wqkv + (size_t)i*768*256 + 480*256; K=240; N=240; Kpad=256; }
        else if (w == 3) { src = Wo + (size_t)i*240*240; dst = WoT + (size_t)i*256*256;            K=240; N=256; Kpad=256; }
        else if (w == 4) { src = W1 + (size_t)i*240*480; dst = W1T + (size_t)i*512*256;            K=240; N=480; Kpad=256; }
        else             { src = W2 + (size_t)i*480*240; dst = W2T + (size_t)i*256*480;            K=480; N=256; Kpad=480; }
    }
    int n0 = blockIdx.x * 64;
    if (n0 >= N) return;
    int realN = (N == 256) ? 240 : N;
    __shared__ float tile[64][65];
    const int tid = threadIdx.x;
    const int lrow = tid >> 4;          // 0..15
    const int lcol = (tid & 15) * 4;    // 0..60
    const int wn   = tid >> 2;          // 0..63
    const int wq   = tid & 3;           // k-quarter
    for (int k0 = 0; k0 < Kpad; k0 += 64) {
        #pragma unroll
        for (int r4 = 0; r4 < 4; r4++) {
            int row = k0 + r4 * 16 + lrow;
            float4 v = {0.f, 0.f, 0.f, 0.f};
            if (row < K && n0 + lcol < realN)
                v = *(const float4*)(src + (size_t)row * realN + n0 + lcol);
            tile[r4 * 16 + lrow][lcol]     = v.x;
            tile[r4 * 16 + lrow][lcol + 1] = v.y;
            tile[r4 * 16 + lrow][lcol + 2] = v.z;
            tile[r4 * 16 + lrow][lcol + 3] = v.w;
        }
        __syncthreads();
        int n = n0 + wn;
        int kbase = k0 + wq * 16;
        if (n < N && kbase < Kpad) {
            unsigned short tmp[16];
            #pragma unroll
            for (int kk = 0; kk < 16; kk++)
                tmp[kk] = f2bf(tile[wq * 16 + kk][wn]);
            *(uint4*)(dst + (size_t)n * Kpad + kbase)     = *(uint4*)&tmp[0];
            *(uint4*)(dst + (size_t)n * Kpad + kbase + 8) = *(uint4*)&tmp[8];
        }
        __syncthreads();
    }
}

// ---------------- MFMA GEMM: C = A[M,Kpad]bf16 @ Bt[N,Kpad]bf16 --------------
// tile 128x64, 4 waves (2x2), K-step 32, double-buffered LDS + counted vmcnt.
// Block->tile mapping is XCD-chunk swizzled (bijective) with y-fastest order.
// flags: 1 relu, 2 accumulate fp32 C, 4 QKV-packed epilogue, 8 bf16 out
__global__ __launch_bounds__(256)
void gemm_mfma(const unsigned short* __restrict__ A,
               const unsigned short* __restrict__ Bt,
               const float* __restrict__ bias,
               float* __restrict__ C, unsigned short* __restrict__ Cbf,
               unsigned short* __restrict__ qp, unsigned short* __restrict__ kp,
               unsigned short* __restrict__ vp,
               int M, int N, int Kpad, int Cstride, int flags)
{
    __shared__ __align__(16) unsigned short As[2][128 * 32];   // 16 KB
    __shared__ __align__(16) unsigned short Bs[2][64 * 32];    // 8 KB
    const int tid = threadIdx.x;
    // ---- XCD-chunked swizzle: hw id c=flat%8 owns contiguous work chunk ----
    const int gx = gridDim.x, gy = gridDim.y;
    const int flat = blockIdx.x + gx * blockIdx.y;
    const int total = gx * gy;
    const int q8 = total >> 3, r8 = total & 7;
    const int cx = flat & 7, kx = flat >> 3;
    const int w = (cx < r8) ? (cx * (q8 + 1) + kx)
                            : (r8 * (q8 + 1) + (cx - r8) * q8 + kx);
    const int bmx = w / gy;            // x-tile (shares A across its y's)
    const int bny = w - bmx * gy;      // y-tile (y-fastest in work order)
    const int bm = bmx * 128;
    const int bn = bny * 64;
    const int zs = gridDim.z, zi = blockIdx.z;
    const int wave = tid >> 6, lane = tid & 63;
    const int wm = (wave & 1) * 64, wn = (wave >> 1) * 32;
    const int lq = lane >> 4, lr = lane & 15;

    f32x4 acc[4][2];
    #pragma unroll
    for (int i = 0; i < 4; i++)
        #pragma unroll
        for (int j = 0; j < 2; j++) acc[i][j] = (f32x4){0.f, 0.f, 0.f, 0.f};

    const int srow = lane >> 2;            // 0..15
    const int schk = (lane & 3) << 3;      // 0,8,16,24
    const int nkt = Kpad >> 5;
    const int kt0 = (nkt * zi) / zs;
    const int kt1 = (nkt * (zi + 1)) / zs;

    const unsigned short* ga0 = A + (size_t)(bm + wave * 32 + srow) * Kpad + schk + kt0 * 32;
    const unsigned short* ga1 = A + (size_t)(bm + wave * 32 + 16 + srow) * Kpad + schk + kt0 * 32;
    const unsigned short* gb  = Bt + (size_t)(bn + wave * 16 + srow) * Kpad + schk + kt0 * 32;
    char* sa = (char*)As + wave * 2048;    // per-wave slice of buffer 0
    char* sb = (char*)Bs + wave * 1024;

    #define STAGE_(bu)  do {                       \
        gl2lds16(ga0, sa + (bu) * 8192);           \
        gl2lds16(ga1, sa + (bu) * 8192 + 1024);    \
        gl2lds16(gb,  sb + (bu) * 4096);           \
        ga0 += 32; ga1 += 32; gb += 32;            \
    } while (0)

    STAGE_(0);                                  // prologue: tile kt0 -> buf 0
    int cur = 0;
    for (int kt = kt0; kt < kt1; kt++) {
        if (kt + 1 < kt1) {
            STAGE_(cur ^ 1);                    // prefetch next tile
            asm volatile("s_waitcnt vmcnt(3)" ::: "memory");   // current tile done
        } else {
            asm volatile("s_waitcnt vmcnt(0)" ::: "memory");
        }
        asm volatile("s_barrier" ::: "memory"); // all waves' stage of buf[cur] done
        const unsigned short* Asc = (const unsigned short*)((const char*)As + cur * 8192);
        const unsigned short* Bsc = (const unsigned short*)((const char*)Bs + cur * 4096);
        bf16x8 af[4], bfr[2];
        #pragma unroll
        for (int i = 0; i < 4; i++)
            af[i] = *(const bf16x8*)&Asc[(wm + i * 16 + lr) * 32 + lq * 8];
        #pragma unroll
        for (int j = 0; j < 2; j++)
            bfr[j] = *(const bf16x8*)&Bsc[(wn + j * 16 + lr) * 32 + lq * 8];
        #pragma unroll
        for (int i = 0; i < 4; i++)
            #pragma unroll
            for (int j = 0; j < 2; j++)
                acc[i][j] = __builtin_amdgcn_mfma_f32_16x16x32_bf16(af[i], bfr[j], acc[i][j], 0, 0, 0);
        asm volatile("s_barrier" ::: "memory"); // all waves done reading buf[cur]
        cur ^= 1;
    }
    #undef STAGE_

    if (flags & 4) {                       // QKV packed epilogue (N=720)
        #pragma unroll
        for (int j = 0; j < 2; j++) {
            int n = bn + wn + j * 16 + lr;
            if (n >= N) continue;
            int which = n / 240;
            int rem = n - which * 240;
            int hh = rem / 15;
            int c = rem - hh * 15;
            unsigned short* dst = (which == 0) ? qp : (which == 1) ? kp : vp;
            float bias_n = bias[n];
            float mult = (which == 0) ? (SCALE_ * LOG2E_) : 1.f;
            #pragma unroll
            for (int i = 0; i < 4; i++)
                #pragma unroll
                for (int r = 0; r < 4; r++) {
                    int m = bm + wm + i * 16 + lq * 4 + r;
                    if (m >= M) continue;
                    float s = (acc[i][j][r] + bias_n) * mult;
                    int b = m / LP_, l = m - b * LP_;
                    unsigned short bits = (which == 2) ? f2h(s) : f2bf(s);
                    dst[(((size_t)b * H_ + hh) * LP_ + l) * 16 + c] = bits;
                }
        }
    } else if (flags & 8) {                // bf16 output
        #pragma unroll
        for (int i = 0; i < 4; i++)
            #pragma unroll
            for (int j = 0; j < 2; j++) {
                int n = bn + wn + j * 16 + lr;
                if (n >= N) continue;
                float bias_n = bias ? bias[n] : 0.f;
                #pragma unroll
                for (int r = 0; r < 4; r++) {
                    int m = bm + wm + i * 16 + lq * 4 + r;
                    if (m >= M) continue;
                    float s = acc[i][j][r] + bias_n;
                    if (flags & 1) s = fmaxf(s, 0.f);
                    Cbf[(size_t)m * Cstride + n] = f2bf(s);
                }
            }
    } else {                               // fp32 output (optionally accumulate)
        #pragma unroll
        for (int i = 0; i < 4; i++)
            #pragma unroll
            for (int j = 0; j < 2; j++) {
                int n = bn + wn + j * 16 + lr;
                if (n >= N) continue;
                float bias_n = (bias && zi == 0) ? bias[n] : 0.f;
                #pragma unroll
                for (int r = 0; r < 4; r++) {
                    int m = bm + wm + i * 16 + lq * 4 + r;
                    if (m >= M) continue;
                    float s = acc[i][j][r] + bias_n;
                    if (flags & 1) s = fmaxf(s, 0.f);
                    size_t off = (size_t)m * Cstride + n;
                    if (flags & 2) {
                        if (zs > 1) atomicAdd(&C[off], s);
                        else C[off] += s;
                    } else C[off] = s;
                }
            }
    }
}

// -------- gemm_rowln480: embed gemm1 + ln480 + relu fused. 128 blocks x 64
// rows, 4 waves x 16 rows x full 480 width, acc[30]. K=192 (6 steps), dbuf.
// Epilogue: v = acc + b1, 480-wide row-LN (16-lane shfl), relu, t480 bf16 out.
__global__ __launch_bounds__(256)
void gemm_rowln480(const unsigned short* __restrict__ A,
                   const unsigned short* __restrict__ Bt,
                   const float* __restrict__ bias,
                   const float* __restrict__ lng, const float* __restrict__ lnb,
                   unsigned short* __restrict__ outbf)
{
    __shared__ __align__(16) unsigned short As[2][64 * 32];    // 8 KB
    __shared__ __align__(16) unsigned short Bs[2][512 * 32];   // 64 KB
    const int tid = threadIdx.x;
    const int bm = blockIdx.x * 64;
    const int wave = tid >> 6, lane = tid & 63;
    const int wm = wave * 16;
    const int lq = lane >> 4, lr = lane & 15;
    const int srow = lane >> 2, schk = (lane & 3) << 3;
    const int Kpad = 192;

    f32x4 acc[30];
    #pragma unroll
    for (int j = 0; j < 30; j++) acc[j] = (f32x4){0.f, 0.f, 0.f, 0.f};

    const unsigned short* ga0 = A + (size_t)(bm + wm + srow) * Kpad + schk;
    const unsigned short* gb0 = Bt + (size_t)(wave * 128 + srow) * Kpad + schk;
    char* sa = (char*)As + wave * 1024;

    #define STAGE_(bu)  do {                                                   \
        if (wave < 2 || true) gl2lds16(ga0, sa + (bu) * 4096);                 \
        _Pragma("unroll")                                                      \
        for (int s = 0; s < 8; s++)                                            \
            gl2lds16(gb0 + (size_t)s * 16 * Kpad,                              \
                     (char*)&Bs[bu][0] + (wave * 8 + s) * 1024);               \
        ga0 += 32; gb0 += 32;                                                  \
    } while (0)

    STAGE_(0);
    int cur = 0;
    for (int kt = 0; kt < 6; kt++) {
        if (kt + 1 < 6) {
            STAGE_(cur ^ 1);
            asm volatile("s_waitcnt vmcnt(9)" ::: "memory");
        } else {
            asm volatile("s_waitcnt vmcnt(0)" ::: "memory");
        }
        asm volatile("s_barrier" ::: "memory");
        bf16x8 af = *(const bf16x8*)&As[cur][(wm + lr) * 32 + lq * 8];
        #pragma unroll
        for (int j = 0; j < 30; j++) {
            bf16x8 bf = *(const bf16x8*)&Bs[cur][(j * 16 + lr) * 32 + lq * 8];
            acc[j] = __builtin_amdgcn_mfma_f32_16x16x32_bf16(af, bf, acc[j], 0, 0, 0);
        }
        asm volatile("s_barrier" ::: "memory");
        cur ^= 1;
    }
    #undef STAGE_

    // ---- epilogue: bias + 480-wide row-LN + relu -> outbf [row][480] ----
    float biasj[30], gj[30], bj[30];
    #pragma unroll
    for (int j = 0; j < 30; j++) {
        int n = j * 16 + lr;
        biasj[j] = bias[n];
        gj[j] = lng[n];
        bj[j] = lnb[n];
    }
    #pragma unroll
    for (int r = 0; r < 4; r++) {
        const int row = bm + wm + lq * 4 + r;
        float v[30];
        float s = 0.f;
        #pragma unroll
        for (int j = 0; j < 30; j++) {
            v[j] = acc[j][r] + biasj[j];
            s += v[j];
        }
        s += __shfl_xor(s, 1); s += __shfl_xor(s, 2);
        s += __shfl_xor(s, 4); s += __shfl_xor(s, 8);
        const float mean = s * (1.f / 480.f);
        float q = 0.f;
        #pragma unroll
        for (int j = 0; j < 30; j++) { float d = v[j] - mean; q += d * d; }
        q += __shfl_xor(q, 1); q += __shfl_xor(q, 2);
        q += __shfl_xor(q, 4); q += __shfl_xor(q, 8);
        const float rs = rsqrtf(q * (1.f / 480.f) + 1e-5f);
        #pragma unroll
        for (int j = 0; j < 30; j++)
            outbf[(size_t)row * 480 + j * 16 + lr] =
                f2bf(fmaxf((v[j] - mean) * rs * gj[j] + bj[j], 0.f));
    }
}

// -------- gemm_row_ln: full-row tile 64x240 (N padded 256), one block per
// 64 rows, 4 waves x 16 rows x full width, acc[16]. Epilogue:
// v = acc + bias + h (residual), h = v, in-register row-LN (shfl over the
// 16 lr-lanes that share a row: col=lr, row=lq*4+r), ybf = LN(v) bf16.
// flags: 1 = write ybf (LN output); else h-update only.
__global__ __launch_bounds__(256)
void gemm_row_ln(const unsigned short* __restrict__ A,
                 const unsigned short* __restrict__ Bt,
                 const float* __restrict__ bias,
                 float* __restrict__ h, unsigned short* __restrict__ ybf,
                 const float* __restrict__ lng, const float* __restrict__ lnb,
                 int M, int Kpad, int flags)
{
    __shared__ __align__(16) unsigned short As[2][64 * 32];    // 8 KB
    __shared__ __align__(16) unsigned short Bs[2][256 * 32];   // 32 KB
    const int tid = threadIdx.x;
    const int bm = blockIdx.x * 64;
    const int wave = tid >> 6, lane = tid & 63;
    const int wm = wave * 16;
    const int lq = lane >> 4, lr = lane & 15;
    const int srow = lane >> 2, schk = (lane & 3) << 3;
    const int nkt = Kpad >> 5;

    f32x4 acc[16];
    #pragma unroll
    for (int j = 0; j < 16; j++) acc[j] = (f32x4){0.f, 0.f, 0.f, 0.f};

    const unsigned short* ga0 = A + (size_t)(bm + wm + srow) * Kpad + schk;
    const unsigned short* gb0 = Bt + (size_t)(wave * 64 + srow) * Kpad + schk;
    char* sa = (char*)As + wave * 1024;
    char* sb = (char*)Bs + wave * 4096;

    #define STAGE_(bu)  do {                                      \
        gl2lds16(ga0, sa + (bu) * 4096);                          \
        gl2lds16(gb0,                   sb + (bu) * 16384);       \
        gl2lds16(gb0 + (size_t)16*Kpad, sb + (bu) * 16384 + 1024);\
        gl2lds16(gb0 + (size_t)32*Kpad, sb + (bu) * 16384 + 2048);\
        gl2lds16(gb0 + (size_t)48*Kpad, sb + (bu) * 16384 + 3072);\
        ga0 += 32; gb0 += 32;                                     \
    } while (0)

    STAGE_(0);
    int cur = 0;
    for (int kt = 0; kt < nkt; kt++) {
        if (kt + 1 < nkt) {
            STAGE_(cur ^ 1);
            asm volatile("s_waitcnt vmcnt(5)" ::: "memory");
        } else {
            asm volatile("s_waitcnt vmcnt(0)" ::: "memory");
        }
        asm volatile("s_barrier" ::: "memory");
        const unsigned short* Asc = (const unsigned short*)((const char*)As + cur * 4096);
        const unsigned short* Bsc = (const unsigned short*)((const char*)Bs + cur * 16384);
        bf16x8 af = *(const bf16x8*)&Asc[(wm + lr) * 32 + lq * 8];
        #pragma unroll
        for (int j = 0; j < 16; j++) {
            bf16x8 bf = *(const bf16x8*)&Bsc[(j * 16 + lr) * 32 + lq * 8];
            acc[j] = __builtin_amdgcn_mfma_f32_16x16x32_bf16(af, bf, acc[j], 0, 0, 0);
        }
        asm volatile("s_barrier" ::: "memory");
        cur ^= 1;
    }
    #undef STAGE_

    // ---- epilogue: residual + h write + in-register row-LN -> ybf ----
    float biasj[15], gj[15], bj[15];
    #pragma unroll
    for (int j = 0; j < 15; j++) {
        int n = j * 16 + lr;
        biasj[j] = bias[n];
        if (flags & 1) { gj[j] = lng[n]; bj[j] = lnb[n]; }
    }
    #pragma unroll
    for (int r = 0; r < 4; r++) {
        const int row = bm + wm + lq * 4 + r;
        if (row >= M) continue;          // uniform across the 16 lr-lanes
        float v[15];
        float s = 0.f;
        #pragma unroll
        for (int j = 0; j < 15; j++) {
            v[j] = acc[j][r] + biasj[j] + h[(size_t)row * 240 + j * 16 + lr];
            s += v[j];
        }
        s += __shfl_xor(s, 1); s += __shfl_xor(s, 2);
        s += __shfl_xor(s, 4); s += __shfl_xor(s, 8);
        #pragma unroll
        for (int j = 0; j < 15; j++)
            h[(size_t)row * 240 + j * 16 + lr] = v[j];
        if (flags & 1) {
            const float mean = s * (1.f / 240.f);
            float q = 0.f;
            #pragma unroll
            for (int j = 0; j < 15; j++) { float d = v[j] - mean; q += d * d; }
            q += __shfl_xor(q, 1); q += __shfl_xor(q, 2);
            q += __shfl_xor(q, 4); q += __shfl_xor(q, 8);
            const float rs = rsqrtf(q * (1.f / 240.f) + 1e-5f);
            #pragma unroll
            for (int j = 0; j < 15; j++)
                ybf[(size_t)row * 256 + j * 16 + lr] =
                    f2bf((v[j] - mean) * rs * gj[j] + bj[j]);
            ybf[(size_t)row * 256 + 240 + lr] = 0;   // pad cols
        }
    }
}

// -------- ffn_fused: per block 32 rows (257 blocks = 8224 exactly).
// Phase 1: t = relu(ybf[32x256] @ W1T^T + b1) -> LDS bf16 [32][488].
//   DOUBLE-buffered staging + counted vmcnt; Tl ALIASES B1 buffer 0 (written
//   only after phase-1's final barrier) so total LDS = 68 KB -> 2 blocks/CU.
// Phase 2: out = t @ W2T^T (K=480, 15 steps); waves 0,1 compute (acc2[15]);
//   B2 double-buffered inside B1 buffer 1's 32 KB.
//   Epilogue = residual + h + row-LN -> ybf (flags&1), same as gemm_row_ln.
__global__ __launch_bounds__(256)
void ffn_fused(const unsigned short* __restrict__ ybf_in,
               const unsigned short* __restrict__ W1t,
               const float* __restrict__ b1,
               const unsigned short* __restrict__ W2t,
               const float* __restrict__ b2,
               float* __restrict__ h, unsigned short* __restrict__ ybf,
               const float* __restrict__ lng, const float* __restrict__ lnb,
               int flags)
{
    __shared__ __align__(16) char S_[69632];   // 68 KB arena -> 2 blocks/CU
    // layout: [0,4K) Ad dbuf [2][2KB]; [4K,36K) B1 buf0 (aliased by Tl);
    //         [36K,68K) B1 buf1 (phase2: B2 dbuf [2][16KB])
    unsigned short* Tl = (unsigned short*)(S_ + 4096);   // [32][488] = 31.2 KB
    const int tid = threadIdx.x;
    const int bm = blockIdx.x * 32;
    const int wave = tid >> 6, lane = tid & 63;
    const int rg = wave >> 1, ch = wave & 1;   // row-group, col-half
    const int lq = lane >> 4, lr = lane & 15;
    const int srow = lane >> 2, schk = (lane & 3) << 3;

    // ---------------- phase 1: t = relu(ybf @ W1T + b1) ----------------
    f32x4 acc1[15];
    #pragma unroll
    for (int j = 0; j < 15; j++) acc1[j] = (f32x4){0.f, 0.f, 0.f, 0.f};

    const unsigned short* gaA = ybf_in + (size_t)(bm + wave * 16 + srow) * 256 + schk;
    const unsigned short* gb1 = W1t + (size_t)(wave * 128 + srow) * 256 + schk;

    #define STAGE1_(bu)  do {                                                  \
        if (wave < 2) gl2lds16(gaA, S_ + (bu) * 2048 + wave * 1024);           \
        _Pragma("unroll")                                                      \
        for (int s = 0; s < 8; s++)                                            \
            gl2lds16(gb1 + (size_t)s * 16 * 256,                               \
                     S_ + 4096 + (bu) * 32768 + (wave * 8 + s) * 1024);        \
        gaA += 32; gb1 += 32;                                                  \
    } while (0)

    STAGE1_(0);
    int cur = 0;
    for (int kt = 0; kt < 8; kt++) {
        if (kt + 1 < 8) {
            STAGE1_(cur ^ 1);
            if (wave < 2) { asm volatile("s_waitcnt vmcnt(9)" ::: "memory"); }
            else          { asm volatile("s_waitcnt vmcnt(8)" ::: "memory"); }
        } else {
            asm volatile("s_waitcnt vmcnt(0)" ::: "memory");
        }
        asm volatile("s_barrier" ::: "memory");
        const unsigned short* Adc = (const unsigned short*)(S_ + cur * 2048);
        const unsigned short* B1c = (const unsigned short*)(S_ + 4096 + cur * 32768);
        bf16x8 af = *(const bf16x8*)&Adc[(rg * 16 + lr) * 32 + lq * 8];
        #pragma unroll
        for (int j = 0; j < 15; j++) {
            bf16x8 bf = *(const bf16x8*)&B1c[(ch * 240 + j * 16 + lr) * 32 + lq * 8];
            acc1[j] = __builtin_amdgcn_mfma_f32_16x16x32_bf16(af, bf, acc1[j], 0, 0, 0);
        }
        asm volatile("s_barrier" ::: "memory");
        cur ^= 1;
    }
    #undef STAGE1_

    // write t = relu(acc1 + b1) to LDS bf16 [32][488] (aliases B1 buf0;
    // safe: all waves are past their last B1 reads after the final barrier)
    #pragma unroll
    for (int j = 0; j < 15; j++) {
        const int col = ch * 240 + j * 16 + lr;
        const float bb = b1[col];
        #pragma unroll
        for (int r = 0; r < 4; r++) {
            const int row = rg * 16 + lq * 4 + r;
            Tl[row * 488 + col] = f2bf(fmaxf(acc1[j][r] + bb, 0.f));
        }
    }
    __syncthreads();   // t complete; B1 buf1 region now reusable as B2 dbuf

    // ---------------- phase 2: out = t @ W2T + b2, residual + LN --------
    f32x4 acc2[15];
    #pragma unroll
    for (int j = 0; j < 15; j++) acc2[j] = (f32x4){0.f, 0.f, 0.f, 0.f};

    const unsigned short* gb2 = W2t + (size_t)(wave * 64 + srow) * 480 + schk;
    char* B2base = S_ + 4096 + 32768;          // [2][16KB] dbuf in B1 buf1

    #define STAGE2_(bu)  do {                                                  \
        _Pragma("unroll")                                                      \
        for (int s = 0; s < 4; s++)                                            \
            gl2lds16(gb2 + (size_t)s * 16 * 480,                               \
                     B2base + (bu) * 16384 + (wave * 4 + s) * 1024);           \
        gb2 += 32;                                                             \
    } while (0)

    STAGE2_(0);
    cur = 0;
    for (int kt = 0; kt < 15; kt++) {
        if (kt + 1 < 15) {
            STAGE2_(cur ^ 1);
            asm volatile("s_waitcnt vmcnt(4)" ::: "memory");
        } else {
            asm volatile("s_waitcnt vmcnt(0)" ::: "memory");
        }
        asm volatile("s_barrier" ::: "memory");
        if (wave < 2) {
            const unsigned short* B2c = (const unsigned short*)(B2base + cur * 16384);
            bf16x8 af = *(const bf16x8*)&Tl[(wave * 16 + lr) * 488 + kt * 32 + lq * 8];
            #pragma unroll
            for (int j = 0; j < 15; j++) {
                bf16x8 bf = *(const bf16x8*)&B2c[(j * 16 + lr) * 32 + lq * 8];
                acc2[j] = __builtin_amdgcn_mfma_f32_16x16x32_bf16(af, bf, acc2[j], 0, 0, 0);
            }
        }
        asm volatile("s_barrier" ::: "memory");
        cur ^= 1;
    }
    #undef STAGE2_

    if (wave >= 2) return;
    // epilogue: rows bm + wave*16 + lq*4 + r  (identical math to gemm_row_ln)
    float biasj[15], gj[15], bj[15];
    #pragma unroll
    for (int j = 0; j < 15; j++) {
        int n = j * 16 + lr;
        biasj[j] = b2[n];
        if (flags & 1) { gj[j] = lng[n]; bj[j] = lnb[n]; }
    }
    #pragma unroll
    for (int r = 0; r < 4; r++) {
        const int row = bm + wave * 16 + lq * 4 + r;
        float v[15];
        float s = 0.f;
        #pragma unroll
        for (int j = 0; j < 15; j++) {
            v[j] = acc2[j][r] + biasj[j] + h[(size_t)row * 240 + j * 16 + lr];
            s += v[j];
        }
        s += __shfl_xor(s, 1); s += __shfl_xor(s, 2);
        s += __shfl_xor(s, 4); s += __shfl_xor(s, 8);
        #pragma unroll
        for (int j = 0; j < 15; j++)
            h[(size_t)row * 240 + j * 16 + lr] = v[j];
        if (flags & 1) {
            const float mean = s * (1.f / 240.f);
            float q = 0.f;
            #pragma unroll
            for (int j = 0; j < 15; j++) { float d = v[j] - mean; q += d * d; }
            q += __shfl_xor(q, 1); q += __shfl_xor(q, 2);
            q += __shfl_xor(q, 4); q += __shfl_xor(q, 8);
            const float rs = rsqrtf(q * (1.f / 240.f) + 1e-5f);
            #pragma unroll
            for (int j = 0; j < 15; j++)
                ybf[(size_t)row * 256 + j * 16 + lr] =
                    f2bf((v[j] - mean) * rs * gj[j] + bj[j]);
            ybf[(size_t)row * 256 + 240 + lr] = 0;   // pad cols
        }
    }
}

// -------- embed finish: wave-per-row LN(g2)+relu+pos (cls for l==0),
// then layer-0 ln1 of the same row in-register -> ybf. lanes 60..62 also
// write q/k/v col-15 constants (replaces attn_init).
__global__ __launch_bounds__(256)
void embed_finish(const float* __restrict__ tmp, const float* __restrict__ mask,
                  const float* __restrict__ g, const float* __restrict__ bb,
                  const float* __restrict__ pos, const float* __restrict__ cls,
                  const float* __restrict__ l1g, const float* __restrict__ l1b,
                  float* __restrict__ h, unsigned short* __restrict__ ybf,
                  unsigned short* __restrict__ qp, unsigned short* __restrict__ kp,
                  unsigned short* __restrict__ vp) {
    const int row = blockIdx.x * 4 + (threadIdx.x >> 6);
    const int lane = threadIdx.x & 63;
    const int b = row / LP_, l = row - b * LP_;
    float* outr = h + (size_t)row * 240;

    if (lane >= 60 && lane <= 62) {
        unsigned short bits;
        unsigned short* dst;
        if (lane == 60) { bits = f2bf(LOG2E_); dst = qp; }
        else if (lane == 61) { bits = (mask[row] != 0.f) ? f2bf(-10000.f) : 0; dst = kp; }
        else { bits = f2h(1.f); dst = vp; }
        #pragma unroll
        for (int hh = 0; hh < H_; hh++)
            dst[(((size_t)b * H_ + hh) * LP_ + l) * 16 + 15] = bits;
    }

    float4 o = {0.f, 0.f, 0.f, 0.f};
    if (l == 0) {
        if (lane < 60) o = *(const float4*)(cls + lane * 4);
    } else {
        const float* x = tmp + ((size_t)b * L_ + (l - 1)) * 240;
        float4 v = {0.f, 0.f, 0.f, 0.f};
        if (lane < 60) v = *(const float4*)(x + lane * 4);
        float s = (v.x + v.y) + (v.z + v.w);
        #pragma unroll
        for (int off = 32; off; off >>= 1) s += __shfl_xor(s, off);
        const float mean = s * (1.f / 240.f);
        float4 d;
        d.x = v.x - mean; d.y = v.y - mean; d.z = v.z - mean; d.w = v.w - mean;
        float vs = (lane < 60) ? (d.x * d.x + d.y * d.y) + (d.z * d.z + d.w * d.w) : 0.f;
        #pragma unroll
        for (int off = 32; off; off >>= 1) vs += __shfl_xor(vs, off);
        const float rs = rsqrtf(vs * (1.f / 240.f) + 1e-5f);
        if (lane < 60) {
            float4 g4 = *(const float4*)(g + lane * 4);
            float4 b4 = *(const float4*)(bb + lane * 4);
            float4 p4 = *(const float4*)(pos + (size_t)(l - 1) * 240 + lane * 4);
            o.x = fmaxf(d.x * rs * g4.x + b4.x, 0.f) + p4.x;
            o.y = fmaxf(d.y * rs * g4.y + b4.y, 0.f) + p4.y;
            o.z = fmaxf(d.z * rs * g4.z + b4.z, 0.f) + p4.z;
            o.w = fmaxf(d.w * rs * g4.w + b4.w, 0.f) + p4.w;
        }
    }
    if (lane < 60) *(float4*)(outr + lane * 4) = o;

    // ---- layer-0 ln1 of this row (value already in registers) ----
    float s1 = (o.x + o.y) + (o.z + o.w);
    #pragma unroll
    for (int off = 32; off; off >>= 1) s1 += __shfl_xor(s1, off);
    const float mean1 = s1 * (1.f / 240.f);
    float4 d1;
    d1.x = o.x - mean1; d1.y = o.y - mean1; d1.z = o.z - mean1; d1.w = o.w - mean1;
    float vs1 = (lane < 60) ? (d1.x * d1.x + d1.y * d1.y) + (d1.z * d1.z + d1.w * d1.w) : 0.f;
    #pragma unroll
    for (int off = 32; off; off >>= 1) vs1 += __shfl_xor(vs1, off);
    const float rs1 = rsqrtf(vs1 * (1.f / 240.f) + 1e-5f);
    ushort4 o4 = {0, 0, 0, 0};
    if (lane < 60) {
        float4 g4 = *(const float4*)(l1g + lane * 4);
        float4 b4 = *(const float4*)(l1b + lane * 4);
        o4.x = f2bf(d1.x * rs1 * g4.x + b4.x);
        o4.y = f2bf(d1.y * rs1 * g4.y + b4.y);
        o4.z = f2bf(d1.z * rs1 * g4.z + b4.z);
        o4.w = f2bf(d1.w * rs1 * g4.w + b4.w);
    }
    *(ushort4*)(ybf + (size_t)row * 256 + lane * 4) = o4;
}

// ---------------- MFMA flash attention: block per (b,h), 4 waves -------------
__global__ __launch_bounds__(256)
void attn_mfma(const unsigned short* __restrict__ qp, const unsigned short* __restrict__ kp,
               const unsigned short* __restrict__ vp, unsigned short* __restrict__ obf)
{
    __shared__ __align__(16) unsigned short Kl[KP_ * 24];    // 13.5 KB
    __shared__ __align__(16) unsigned short Vt[16 * 296];    // 9.25 KB  V^T f16
    __shared__ __align__(16) unsigned short Pl[4][16 * 296]; // 37 KB    P f16 per wave
    const int hh = blockIdx.x, b = blockIdx.y;
    const int tid = threadIdx.x;
    const int wave = tid >> 6, lane = tid & 63;
    const int lq = lane >> 4, lr = lane & 15;
    const size_t base = ((size_t)b * H_ + hh) * LP_ * 16;

    for (int key = tid; key < KP_; key += 256) {
        uint4 z = {0u, 0u, 0u, 0u};
        uint4 k0 = z, k1 = z, v0 = z, v1 = z;
        if (key < LP_) {
            k0 = *(const uint4*)(kp + base + (size_t)key * 16);
            k1 = *(const uint4*)(kp + base + (size_t)key * 16 + 8);
            v0 = *(const uint4*)(vp + base + (size_t)key * 16);
            v1 = *(const uint4*)(vp + base + (size_t)key * 16 + 8);
        } else {
            k1.w = 0xC61C0000u;            // elem15 = bf16(-10000) sentinel
        }
        *(uint4*)&Kl[key * 24] = k0;
        *(uint4*)&Kl[key * 24 + 8] = k1;
        unsigned short vs[8];
        *(uint4*)vs = v0;
        #pragma unroll
        for (int d = 0; d < 8; d++) Vt[d * 296 + key] = vs[d];
        *(uint4*)vs = v1;
        #pragma unroll
        for (int d = 0; d < 8; d++) Vt[(d + 8) * 296 + key] = vs[d];
    }
    __syncthreads();

    unsigned short* Pw = &Pl[wave][0];
    {   // keys 272..287 are pure padding every qt: zero their P once per wave
        int r = lane >> 2, c0 = 272 + (lane & 3) * 4;
        ushort4 z4 = {0, 0, 0, 0};
        *(ushort4*)&Pw[r * 296 + c0] = z4;
    }
    for (int qt = wave; qt < 17; qt += 4) {
        const int qrow = qt * 16 + lr;
        bf16x8 aq = {0, 0, 0, 0, 0, 0, 0, 0};
        if (lq < 2)
            aq = *(const bf16x8*)(qp + base + (size_t)qrow * 16 + lq * 8);
        for (int kt = 0; kt < 17; kt++) {      // kt=17 tile is all padding: skipped
            bf16x8 bk = {0, 0, 0, 0, 0, 0, 0, 0};
            if (lq < 2)
                bk = *(const bf16x8*)&Kl[(kt * 16 + lr) * 24 + lq * 8];
            f32x4 sacc = {0.f, 0.f, 0.f, 0.f};
            sacc = __builtin_amdgcn_mfma_f32_16x16x32_bf16(aq, bk, sacc, 0, 0, 0);
            #pragma unroll
            for (int r = 0; r < 4; r++)
                Pw[(lq * 4 + r) * 296 + kt * 16 + lr] = f2h(exp2f(sacc[r]));
        }
        asm volatile("s_waitcnt lgkmcnt(0)" ::: "memory");
        f32x4 o = {0.f, 0.f, 0.f, 0.f};
        __builtin_amdgcn_s_setprio(1);
        #pragma unroll
        for (int ks = 0; ks < 9; ks++) {
            f16x8 ap = *(const f16x8*)&Pw[lr * 296 + ks * 32 + lq * 8];
            f16x8 bv = *(const f16x8*)&Vt[lr * 296 + ks * 32 + lq * 8];
            o = __builtin_amdgcn_mfma_f32_16x16x32_f16(ap, bv, o, 0, 0, 0);
        }
        __builtin_amdgcn_s_setprio(0);
        asm volatile("s_waitcnt lgkmcnt(0)" ::: "memory");
        #pragma unroll
        for (int r = 0; r < 4; r++) {
            float denom = __shfl(o[r], lane | 15);
            int q = qt * 16 + lq * 4 + r;
            if (q < LP_ && lr < 15)
                obf[((size_t)b * LP_ + q) * 256 + hh * DK_ + lr] = f2bf(o[r] / denom);
        }
    }
    // zero pad cols 240..255 (once per row, by hh==0 block)
    if (hh == 0) {
        for (int q = tid; q < LP_; q += 256) {
            uint4 z = {0u, 0u, 0u, 0u};
            *(uint4*)(obf + ((size_t)b * LP_ + q) * 256 + 240) = z;
            *(uint4*)(obf + ((size_t)b * LP_ + q) * 256 + 248) = z;
        }
    }
}

// ---------------- masked mean pool (partial) ---------------------------------
__global__ void pool_partial(const float* __restrict__ h, const float* __restrict__ mask,
                             float* __restrict__ partial) {
    int b = blockIdx.x, slice = blockIdx.y;
    int d = threadIdx.x;
    if (d >= D_) return;
    float s = 0.f;
    int l0 = slice * 29;
    for (int i = 0; i < 29; i++) {
        int l = l0 + i;
        if (l < LP_ && mask[b * LP_ + l] == 0.f)
            s += h[((size_t)b * LP_ + l) * D_ + d];
    }
    partial[((size_t)b * 9 + slice) * D_ + d] = s;
}

// ---------------- pool finalize + logits -------------------------------------
__global__ __launch_bounds__(256)
void pool_logits(const float* __restrict__ partial, const float* __restrict__ mask,
                 const float* __restrict__ W, const float* __restrict__ bias,
                 float* __restrict__ out) {
    int b = blockIdx.x;
    int t = threadIdx.x;
    __shared__ float red[256];
    __shared__ float pool[240];
    float c = 0.f;
    for (int l = t; l < LP_; l += 256) c += (mask[b * LP_ + l] == 0.f) ? 1.f : 0.f;
    red[t] = c;
    __syncthreads();
    for (int off = 128; off > 0; off >>= 1) {
        if (t < off) red[t] += red[t + off];
        __syncthreads();
    }
    float inv = 1.f / red[0];
    if (t < D_) {
        float s = 0.f;
        #pragma unroll
        for (int sl = 0; sl < 9; sl++) s += partial[((size_t)b * 9 + sl) * D_ + t];
        pool[t] = s * inv;
    }
    __syncthreads();
    if (t < NC_) {
        float s = bias[t];
        for (int kk = 0; kk < D_; kk++) s += pool[kk] * W[(size_t)kk * NC_ + t];
        out[b * NC_ + t] = s;
    }
}

extern "C" void kernel_launch(void* const* d_in, const int* in_sizes, int n_in,
                              void* d_out, int out_size, void* d_ws, size_t ws_size,
                              hipStream_t stream) {
    const float* x        = (const float*)d_in[0];
    const float* pos      = (const float*)d_in[1];
    const float* cls      = (const float*)d_in[2];
    const float* e_W1     = (const float*)d_in[3];
    const float* e_b1     = (const float*)d_in[4];
    const float* e_g1     = (const float*)d_in[5];
    const float* e_bn1    = (const float*)d_in[6];
    const float* e_W2     = (const float*)d_in[7];
    const float* e_b2     = (const float*)d_in[8];
    const float* e_g2     = (const float*)d_in[9];
    const float* e_bn2    = (const float*)d_in[10];
    const float* ln1_g    = (const float*)d_in[11];
    const float* ln1_b    = (const float*)d_in[12];
    const float* Wq       = (const float*)d_in[13];
    const float* bq       = (const float*)d_in[14];
    const float* Wk       = (const float*)d_in[15];
    const float* bk       = (const float*)d_in[16];
    const float* Wv       = (const float*)d_in[17];
    const float* bv       = (const float*)d_in[18];
    const float* Wo       = (const float*)d_in[19];
    const float* bo       = (const float*)d_in[20];
    const float* ln2_g    = (const float*)d_in[21];
    const float* ln2_b    = (const float*)d_in[22];
    const float* W1       = (const float*)d_in[23];
    const float* b1       = (const float*)d_in[24];
    const float* W2       = (const float*)d_in[25];
    const float* b2       = (const float*)d_in[26];
    const float* logit_W  = (const float*)d_in[27];
    const float* logit_b  = (const float*)d_in[28];
    float* out = (float*)d_out;

    const size_t TOK  = (size_t)B_ * LP_;            // 8224
    const size_t TOKP = 8320;                        // padded to 65*128
    const size_t HN   = TOK * D_;
    const size_t QN   = (size_t)B_ * H_ * LP_ * 16;  // 2,105,344

    char* wsb = (char*)d_ws;
    size_t cur = 0;
    auto take = [&](size_t bytes) { void* p = wsb + cur; cur += (bytes + 15) & ~15ULL; return p; };
    float* mask = (float*)take(8224 * 4);
    float* h    = (float*)take(HN * 4);
    float* b720 = (float*)take(NB_ * 720 * 4);
    float* part = (float*)take((size_t)B_ * 9 * D_ * 4);
    void* regionA = take((size_t)8192 * 480 * 4);
    float* y32 = (float*)regionA;                    // embed gemm2 fp32 out
    void* regionB = take(TOKP * 256 * 2 * 2);
    unsigned short* ybf = (unsigned short*)regionB;
    unsigned short* obf = ybf + TOKP * 256;
    unsigned short* xbf  = (unsigned short*)take((size_t)8192 * 192 * 2);
    unsigned short* We1  = (unsigned short*)take((size_t)512 * 192 * 2);
    unsigned short* We2  = (unsigned short*)take((size_t)256 * 480 * 2);
    unsigned short* Wqkv = (unsigned short*)take((size_t)NB_ * 768 * 256 * 2);
    unsigned short* WoT  = (unsigned short*)take((size_t)NB_ * 256 * 256 * 2);
    unsigned short* W1T  = (unsigned short*)take((size_t)NB_ * 512 * 256 * 2);
    unsigned short* W2T  = (unsigned short*)take((size_t)NB_ * 256 * 480 * 2);
    unsigned short* qp = (unsigned short*)take(QN * 3 * 2 + 16 * 16 * 2);
    unsigned short* kp = qp + QN;
    unsigned short* vp = kp + QN;
    unsigned short* t480bf = qp;   // aliases qp/kp, dead before embed_finish

    const int BS = 256;

    // prep (2 dispatches)
    prep_misc<<<8192 + NB_ + 129, 64, 0, stream>>>(x, xbf, bq, bk, bv, b720, mask);
    prep_weights<<<dim3(8, 38), BS, 0, stream>>>(e_W1, e_W2, Wq, Wk, Wv, Wo, W1, W2,
                                                 We1, We2, Wqkv, WoT, W1T, W2T);

    // embed: gemm1+ln480+relu fused -> t480bf; gemm2 -> y32; finish -> h,ybf
    gemm_rowln480<<<128, BS, 0, stream>>>(xbf, We1, e_b1, e_g1, e_bn1, t480bf);
    gemm_mfma<<<dim3(64, 4), BS, 0, stream>>>(t480bf, We2, e_b2, y32, nullptr,
                                              nullptr, nullptr, nullptr,
                                              8192, 240, 480, 240, 0);
    embed_finish<<<(int)(TOK / 4), BS, 0, stream>>>(y32, mask, e_g2, e_bn2, pos, cls,
                                                    ln1_g, ln1_b, h, ybf, qp, kp, vp);

    for (int i = 0; i < NB_; i++) {
        gemm_mfma<<<dim3(65, 12), BS, 0, stream>>>(ybf, Wqkv + (size_t)i * 768 * 256,
                                                   b720 + i * 720, nullptr, nullptr,
                                                   qp, kp, vp,
                                                   (int)TOK, 720, 256, 0, 4);
        attn_mfma<<<dim3(H_, B_), BS, 0, stream>>>(qp, kp, vp, obf);
        // Wo gemm + residual + fused ln2 -> ybf (64-row tile)
        gemm_row_ln<<<129, BS, 0, stream>>>(obf, WoT + (size_t)i * 256 * 256,
                                            bo + i * D_, h, ybf,
                                            ln2_g + i * D_, ln2_b + i * D_,
                                            (int)TOK, 256, 1);
        // FFN1 + FFN2 + residual + fused ln1(i+1) in ONE kernel (dbuf, 68KB)
        ffn_fused<<<257, BS, 0, stream>>>(ybf, W1T + (size_t)i * 512 * 256,
                                          b1 + i * HID_,
                                          W2T + (size_t)i * 256 * 480,
                                          b2 + i * D_, h, ybf,
                                          ln1_g + ((i + 1) % NB_) * D_,
                                          ln1_b + ((i + 1) % NB_) * D_,
                                          (i < NB_ - 1) ? 1 : 0);
    }

    pool_partial<<<dim3(B_, 9), BS, 0, stream>>>(h, mask, part);
    pool_logits<<<B_, BS, 0, stream>>>(part, mask, logit_W, logit_b, out);
}